// Round 2
// baseline (5792.825 us; speedup 1.0000x reference)
//
#include <hip/hip_runtime.h>
#include <hip/hip_bf16.h>
#include <stdint.h>

// ---------------------------------------------------------------------------
// 2-layer GCN on MI355X (gfx950).
// Round 2 structure: bf16x3 split-precision MFMA GEMM (no fp32 MFMA on CDNA4)
// + atomic edge scatter + fused self-loop epilogues.
//
//   dinv = rsqrt(1 + indegree)
//   h  = x @ W1          (MFMA: x split hi/lo bf16 on the fly, W pre-split)
//   agg[dst] += h[src]*dinv[src]*dinv[dst]
//   h1 = relu(agg + h*dinv^2 + b1)
//   h2 = h1 @ W2
//   out[dst] += h2[src]*norm ;  out += h2*dinv^2 + b2
//
// Workspace requirement: ~104 MB (dinv + two N*256 f32 buffers + split weights)
// ---------------------------------------------------------------------------

#define C_OUT 256
#define BM 64          // GEMM rows per block
#define BK 32          // GEMM k-step
#define LDW 40         // LDS row stride in shorts (32 + 8 pad -> 16B aligned)

typedef short  short8  __attribute__((ext_vector_type(8)));
typedef short  short4v __attribute__((ext_vector_type(4)));
typedef float  f32x4   __attribute__((ext_vector_type(4)));

static __device__ __forceinline__ short f32_to_bf16_rne(float f) {
    uint32_t u = __builtin_bit_cast(uint32_t, f);
    uint32_t r = 0x7FFFu + ((u >> 16) & 1u);
    return (short)((u + r) >> 16);
}
static __device__ __forceinline__ float bf16_to_f32(short s) {
    uint32_t u = ((uint32_t)(uint16_t)s) << 16;
    return __builtin_bit_cast(float, u);
}

// ---------------------------- degree / dinv --------------------------------
__global__ __launch_bounds__(256) void deg_init_kernel(float* __restrict__ deg, int n) {
    int i = blockIdx.x * blockDim.x + threadIdx.x;
    if (i < n) deg[i] = 1.0f;              // self-loop
}
__global__ __launch_bounds__(256) void deg_edges_kernel(const int* __restrict__ dst,
                                                        float* __restrict__ deg, int nE) {
    int e = blockIdx.x * blockDim.x + threadIdx.x;
    if (e < nE) atomicAdd(&deg[dst[e]], 1.0f);
}
__global__ __launch_bounds__(256) void dinv_kernel(float* __restrict__ deg, int n) {
    int i = blockIdx.x * blockDim.x + threadIdx.x;
    if (i < n) deg[i] = rsqrtf(deg[i]);
}

// ------------------- weight split + transpose (once per launch) ------------
// W1[768][256], W2[256][256] fp32  ->  Wh/Wl [256][K] bf16 (transposed)
__global__ __launch_bounds__(256) void wsplit_kernel(const float* __restrict__ W1,
                                                     const float* __restrict__ W2,
                                                     short* __restrict__ Wh1, short* __restrict__ Wl1,
                                                     short* __restrict__ Wh2, short* __restrict__ Wl2) {
    int i = blockIdx.x * 256 + threadIdx.x;          // grid covers 768*256 + 256*256
    if (i < 768 * 256) {
        int k = i >> 8, n = i & 255;
        float v = W1[i];
        short h = f32_to_bf16_rne(v);
        short l = f32_to_bf16_rne(v - bf16_to_f32(h));
        Wh1[n * 768 + k] = h;
        Wl1[n * 768 + k] = l;
    } else {
        int j = i - 768 * 256;
        int k = j >> 8, n = j & 255;
        float v = W2[j];
        short h = f32_to_bf16_rne(v);
        short l = f32_to_bf16_rne(v - bf16_to_f32(h));
        Wh2[n * 256 + k] = h;
        Wl2[n * 256 + k] = l;
    }
}

// ---------------------------------------------------------------------------
// MFMA GEMM:  C[M,256] = A[M,K] (fp32) @ W[K,256]
// W supplied pre-split/transposed: Bh/Bl = [256][K] bf16.
// acc += Ah*Bh + Ah*Bl + Al*Bh   (bf16x3 split product)
// Block: 256 threads = 4 waves; block tile 64(M) x 256(N); wave tile 64x64.
// mfma_f32_16x16x32_bf16 fragments:
//   A: row = lane&15, k = (lane>>4)*8 + i   (8 contiguous bf16 -> ds_read_b128)
//   B: col = lane&15 (row of W^T), same k grouping
//   C: col = lane&15, row = (lane>>4)*4 + reg     [m89/m91-verified]
// ---------------------------------------------------------------------------
__global__ __launch_bounds__(256) void mfma_gemm_kernel(const float* __restrict__ A,
                                                        const short* __restrict__ Bh,
                                                        const short* __restrict__ Bl,
                                                        float* __restrict__ C,
                                                        int M, int K) {
    __shared__ __align__(16) short AhS[BM][LDW];
    __shared__ __align__(16) short AlS[BM][LDW];
    __shared__ __align__(16) short BhS[C_OUT][LDW];
    __shared__ __align__(16) short BlS[C_OUT][LDW];

    const int tid  = threadIdx.x;
    const int lane = tid & 63;
    const int wid  = tid >> 6;            // 0..3 -> N quadrant
    const int lr   = lane & 15;
    const int kb   = lane >> 4;           // 0..3 k-block of fragment
    const int row0 = blockIdx.x * BM;

    f32x4 acc[4][4];                      // [mf][nf]
#pragma unroll
    for (int i = 0; i < 4; ++i)
#pragma unroll
        for (int j = 0; j < 4; ++j) acc[i][j] = (f32x4){0.f, 0.f, 0.f, 0.f};

    for (int k0 = 0; k0 < K; k0 += BK) {
        // ---- stage A: [64][32] fp32 -> split bf16 hi/lo in LDS ----
#pragma unroll
        for (int it = 0; it < 2; ++it) {
            int flat = tid + it * 256;            // over [64 rows][8 float4-groups]
            int row = flat >> 3, q = flat & 7;
            float4 v = make_float4(0.f, 0.f, 0.f, 0.f);
            if (row0 + row < M)
                v = *(const float4*)&A[(size_t)(row0 + row) * K + k0 + q * 4];
            short4v hi, lo;
            float f[4] = {v.x, v.y, v.z, v.w};
#pragma unroll
            for (int j = 0; j < 4; ++j) {
                short h = f32_to_bf16_rne(f[j]);
                hi[j] = h;
                lo[j] = f32_to_bf16_rne(f[j] - bf16_to_f32(h));
            }
            *(short4v*)&AhS[row][q * 4] = hi;
            *(short4v*)&AlS[row][q * 4] = lo;
        }
        // ---- stage B: [256][32] bf16 from Wh/Wl ----
#pragma unroll
        for (int it = 0; it < 4; ++it) {
            int flat = tid + it * 256;            // over [256 rows][4 short8-groups]
            int row = flat >> 2, g = flat & 3;
            short8 vh = *(const short8*)&Bh[(size_t)row * K + k0 + g * 8];
            short8 vl = *(const short8*)&Bl[(size_t)row * K + k0 + g * 8];
            *(short8*)&BhS[row][g * 8] = vh;
            *(short8*)&BlS[row][g * 8] = vl;
        }
        __syncthreads();

        // ---- fragments + MFMA ----
        short8 ah[4], al[4], bh[4], bl[4];
#pragma unroll
        for (int mf = 0; mf < 4; ++mf) {
            int r = mf * 16 + lr;
            ah[mf] = *(const short8*)&AhS[r][kb * 8];
            al[mf] = *(const short8*)&AlS[r][kb * 8];
        }
#pragma unroll
        for (int nf = 0; nf < 4; ++nf) {
            int r = wid * 64 + nf * 16 + lr;
            bh[nf] = *(const short8*)&BhS[r][kb * 8];
            bl[nf] = *(const short8*)&BlS[r][kb * 8];
        }
#pragma unroll
        for (int mf = 0; mf < 4; ++mf)
#pragma unroll
            for (int nf = 0; nf < 4; ++nf) {
                acc[mf][nf] = __builtin_amdgcn_mfma_f32_16x16x32_bf16(ah[mf], bh[nf], acc[mf][nf], 0, 0, 0);
                acc[mf][nf] = __builtin_amdgcn_mfma_f32_16x16x32_bf16(ah[mf], bl[nf], acc[mf][nf], 0, 0, 0);
                acc[mf][nf] = __builtin_amdgcn_mfma_f32_16x16x32_bf16(al[mf], bh[nf], acc[mf][nf], 0, 0, 0);
            }
        __syncthreads();
    }

    // ---- C write ----
#pragma unroll
    for (int mf = 0; mf < 4; ++mf) {
#pragma unroll
        for (int r = 0; r < 4; ++r) {
            int grow = row0 + mf * 16 + kb * 4 + r;
            if (grow < M) {
                float* cp = &C[(size_t)grow * C_OUT + wid * 64 + lr];
#pragma unroll
                for (int nf = 0; nf < 4; ++nf) cp[nf * 16] = acc[mf][nf][r];
            }
        }
    }
}

// ---------------------------------------------------------------------------
// Edge scatter: one wave per edge; lane l -> channels 4l..4l+3.
// ---------------------------------------------------------------------------
__global__ __launch_bounds__(256) void scatter_kernel(const float* __restrict__ h,
                                                      const int* __restrict__ src,
                                                      const int* __restrict__ dst,
                                                      const float* __restrict__ dinv,
                                                      float* __restrict__ out, int nE) {
    int e = blockIdx.x * 4 + (threadIdx.x >> 6);
    if (e >= nE) return;
    int lane = threadIdx.x & 63;
    int s = src[e];
    int d = dst[e];
    float norm = dinv[s] * dinv[d];
    float4 v = *(const float4*)&h[(size_t)s * C_OUT + (lane << 2)];
    float* op = &out[(size_t)d * C_OUT + (lane << 2)];
    atomicAdd(op + 0, v.x * norm);
    atomicAdd(op + 1, v.y * norm);
    atomicAdd(op + 2, v.z * norm);
    atomicAdd(op + 3, v.w * norm);
}

// h1 = relu(agg + h*dinv^2 + b1)
__global__ __launch_bounds__(256) void epilogue1_kernel(const float* __restrict__ h,
                                                        const float* __restrict__ agg,
                                                        const float* __restrict__ dinv,
                                                        const float* __restrict__ b,
                                                        float* __restrict__ out, int n4) {
    int i = blockIdx.x * blockDim.x + threadIdx.x;
    if (i >= n4) return;
    int node = i >> 6;
    int c4 = (i & 63) << 2;
    float di = dinv[node];
    float w = di * di;
    float4 hv = ((const float4*)h)[i];
    float4 av = ((const float4*)agg)[i];
    float4 bv = *(const float4*)&b[c4];
    float4 r;
    r.x = fmaxf(av.x + hv.x * w + bv.x, 0.f);
    r.y = fmaxf(av.y + hv.y * w + bv.y, 0.f);
    r.z = fmaxf(av.z + hv.z * w + bv.z, 0.f);
    r.w = fmaxf(av.w + hv.w * w + bv.w, 0.f);
    ((float4*)out)[i] = r;
}

// out += h*dinv^2 + b2
__global__ __launch_bounds__(256) void epilogue2_kernel(const float* __restrict__ h,
                                                        const float* __restrict__ dinv,
                                                        const float* __restrict__ b,
                                                        float* __restrict__ out, int n4) {
    int i = blockIdx.x * blockDim.x + threadIdx.x;
    if (i >= n4) return;
    int node = i >> 6;
    int c4 = (i & 63) << 2;
    float di = dinv[node];
    float w = di * di;
    float4 hv = ((const float4*)h)[i];
    float4 ov = ((float4*)out)[i];
    float4 bv = *(const float4*)&b[c4];
    ov.x += hv.x * w + bv.x;
    ov.y += hv.y * w + bv.y;
    ov.z += hv.z * w + bv.z;
    ov.w += hv.w * w + bv.w;
    ((float4*)out)[i] = ov;
}

extern "C" void kernel_launch(void* const* d_in, const int* in_sizes, int n_in,
                              void* d_out, int out_size, void* d_ws, size_t ws_size,
                              hipStream_t stream) {
    const float* x  = (const float*)d_in[0];
    const int* ei   = (const int*)d_in[1];
    const float* W1 = (const float*)d_in[2];
    const float* b1 = (const float*)d_in[3];
    const float* W2 = (const float*)d_in[4];
    const float* b2 = (const float*)d_in[5];
    float* out = (float*)d_out;

    const int K1 = 768;
    const int N  = in_sizes[0] / K1;        // 50000
    const int nE = in_sizes[1] / 2;         // 800000
    const int* src = ei;
    const int* dst = ei + nE;

    // workspace layout
    char* ws = (char*)d_ws;
    size_t off = 0;
    float* dinv = (float*)(ws + off); off += ((size_t)N * 4 + 255) & ~255ull;
    float* bufA = (float*)(ws + off); off += (size_t)N * C_OUT * 4;   // h / h2
    float* bufB = (float*)(ws + off); off += (size_t)N * C_OUT * 4;   // agg / h1
    short* Wh1  = (short*)(ws + off); off += (size_t)768 * 256 * 2;
    short* Wl1  = (short*)(ws + off); off += (size_t)768 * 256 * 2;
    short* Wh2  = (short*)(ws + off); off += (size_t)256 * 256 * 2;
    short* Wl2  = (short*)(ws + off); off += (size_t)256 * 256 * 2;
    const size_t feat_bytes = (size_t)N * C_OUT * sizeof(float);

    const int nb_nodes = (N + 255) / 256;
    const int nb_edges = (nE + 255) / 256;
    const int n4 = N * (C_OUT / 4);
    const int nb_feat = (n4 + 255) / 256;
    const int gemm_blocks = (N + BM - 1) / BM;

    // ---- degrees -> dinv, weight split (independent of gemm1) ----
    deg_init_kernel<<<nb_nodes, 256, 0, stream>>>(dinv, N);
    deg_edges_kernel<<<nb_edges, 256, 0, stream>>>(dst, dinv, nE);
    dinv_kernel<<<nb_nodes, 256, 0, stream>>>(dinv, N);
    wsplit_kernel<<<(768 * 256 + 256 * 256) / 256, 256, 0, stream>>>(W1, W2, Wh1, Wl1, Wh2, Wl2);

    // ---- layer 1 ----
    mfma_gemm_kernel<<<gemm_blocks, 256, 0, stream>>>(x, Wh1, Wl1, bufA, N, K1);
    hipMemsetAsync(bufB, 0, feat_bytes, stream);
    scatter_kernel<<<(nE + 3) / 4, 256, 0, stream>>>(bufA, src, dst, dinv, bufB, nE);
    epilogue1_kernel<<<nb_feat, 256, 0, stream>>>(bufA, bufB, dinv, b1, bufB, n4);

    // ---- layer 2 ----
    mfma_gemm_kernel<<<gemm_blocks, 256, 0, stream>>>(bufB, Wh2, Wl2, bufA, N, C_OUT);
    hipMemsetAsync(out, 0, feat_bytes, stream);
    scatter_kernel<<<(nE + 3) / 4, 256, 0, stream>>>(bufA, src, dst, dinv, out, nE);
    epilogue2_kernel<<<nb_feat, 256, 0, stream>>>(bufA, dinv, b2, out, n4);
}

// Round 3
// 705.010 us; speedup vs baseline: 8.2167x; 8.2167x over previous
//
#include <hip/hip_runtime.h>
#include <hip/hip_bf16.h>
#include <stdint.h>

// ---------------------------------------------------------------------------
// 2-layer GCN on MI355X (gfx950).  Round 3: CSR gather-aggregation (no fp32
// atomics) + bf16x3 split MFMA GEMM with dinv folded into the epilogue.
//
//   count[d] = in-degree ; dinv = rsqrt(count+1)
//   CSR: rowstart = exscan(count) ; srcSorted bucketed by dst
//   hs1 = (x @ W1) * dinv[row]                       (MFMA GEMM, fused scale)
//   h1  = relu(dinv[d]*(hs1[d] + sum_{s->d} hs1[s]) + b1)   (wave-per-node)
//   hs2 = (h1 @ W2) * dinv[row]
//   out = dinv[d]*(hs2[d] + sum hs2[s]) + b2
// ---------------------------------------------------------------------------

#define C_OUT 256
#define BM 64          // GEMM rows per block
#define BK 32          // GEMM k-step
#define LDW 40         // LDS row stride in shorts (32 + 8 pad)

typedef short  short8  __attribute__((ext_vector_type(8)));
typedef short  short4v __attribute__((ext_vector_type(4)));
typedef float  f32x4   __attribute__((ext_vector_type(4)));

static __device__ __forceinline__ short f32_to_bf16_rne(float f) {
    uint32_t u = __builtin_bit_cast(uint32_t, f);
    uint32_t r = 0x7FFFu + ((u >> 16) & 1u);
    return (short)((u + r) >> 16);
}
static __device__ __forceinline__ float bf16_to_f32(short s) {
    uint32_t u = ((uint32_t)(uint16_t)s) << 16;
    return __builtin_bit_cast(float, u);
}

// --------------------------- CSR build ------------------------------------
__global__ __launch_bounds__(256) void count_kernel(const int* __restrict__ dst,
                                                    int* __restrict__ count, int nE) {
    int e = blockIdx.x * blockDim.x + threadIdx.x;
    if (e < nE) atomicAdd(&count[dst[e]], 1);
}

// block-level exclusive scan (Hillis-Steele in LDS), 256/block
__global__ __launch_bounds__(256) void scan1_kernel(const int* __restrict__ count,
                                                    int* __restrict__ rowpart,
                                                    int* __restrict__ bsums, int n) {
    __shared__ int tmp[256];
    int t = threadIdx.x;
    int i = blockIdx.x * 256 + t;
    int v = (i < n) ? count[i] : 0;
    tmp[t] = v;
    __syncthreads();
    for (int off = 1; off < 256; off <<= 1) {
        int u = 0;
        if (t >= off) u = tmp[t - off];
        __syncthreads();
        if (t >= off) tmp[t] += u;
        __syncthreads();
    }
    if (i < n) rowpart[i] = tmp[t] - v;          // exclusive
    if (t == 255) bsums[blockIdx.x] = tmp[255];  // block total
}

// single-block exclusive scan of block sums (nb <= 256)
__global__ __launch_bounds__(256) void scan2_kernel(int* __restrict__ bsums, int nb) {
    __shared__ int tmp[256];
    int t = threadIdx.x;
    int v = (t < nb) ? bsums[t] : 0;
    tmp[t] = v;
    __syncthreads();
    for (int off = 1; off < 256; off <<= 1) {
        int u = 0;
        if (t >= off) u = tmp[t - off];
        __syncthreads();
        if (t >= off) tmp[t] += u;
        __syncthreads();
    }
    if (t < nb) bsums[t] = tmp[t] - v;           // exclusive, in-place
}

// rowstart = rowpart + bscan[blk]; cursor = rowstart; dinv = rsqrt(count+1)
__global__ __launch_bounds__(256) void scan3_kernel(const int* __restrict__ rowpart,
                                                    const int* __restrict__ bsums,
                                                    const int* __restrict__ count,
                                                    int* __restrict__ rowstart,
                                                    int* __restrict__ cursor,
                                                    float* __restrict__ dinv,
                                                    int n, int nE) {
    int i = blockIdx.x * 256 + threadIdx.x;
    if (i < n) {
        int r = rowpart[i] + bsums[blockIdx.x];
        rowstart[i] = r;
        cursor[i] = r;
        dinv[i] = rsqrtf((float)count[i] + 1.0f);
    }
    if (i == 0) rowstart[n] = nE;
}

__global__ __launch_bounds__(256) void fill_kernel(const int* __restrict__ src,
                                                   const int* __restrict__ dst,
                                                   int* __restrict__ cursor,
                                                   int* __restrict__ srcSorted, int nE) {
    int e = blockIdx.x * blockDim.x + threadIdx.x;
    if (e < nE) {
        int p = atomicAdd(&cursor[dst[e]], 1);
        srcSorted[p] = src[e];
    }
}

// ------------------- weight split + transpose (once per launch) ------------
__global__ __launch_bounds__(256) void wsplit_kernel(const float* __restrict__ W1,
                                                     const float* __restrict__ W2,
                                                     short* __restrict__ Wh1, short* __restrict__ Wl1,
                                                     short* __restrict__ Wh2, short* __restrict__ Wl2) {
    int i = blockIdx.x * 256 + threadIdx.x;
    if (i < 768 * 256) {
        int k = i >> 8, n = i & 255;
        float v = W1[i];
        short h = f32_to_bf16_rne(v);
        short l = f32_to_bf16_rne(v - bf16_to_f32(h));
        Wh1[n * 768 + k] = h;
        Wl1[n * 768 + k] = l;
    } else {
        int j = i - 768 * 256;
        int k = j >> 8, n = j & 255;
        float v = W2[j];
        short h = f32_to_bf16_rne(v);
        short l = f32_to_bf16_rne(v - bf16_to_f32(h));
        Wh2[n * 256 + k] = h;
        Wl2[n * 256 + k] = l;
    }
}

// ---------------------------------------------------------------------------
// MFMA GEMM with fused row-scale:  C[M,256] = (A[M,K] @ W[K,256]) * dinv[row]
// acc += Ah*Bh + Ah*Bl + Al*Bh   (bf16x3 split product)
// Block: 256 threads = 4 waves; tile 64(M) x 256(N); wave tile 64x64.
// ---------------------------------------------------------------------------
__global__ __launch_bounds__(256) void mfma_gemm_kernel(const float* __restrict__ A,
                                                        const short* __restrict__ Bh,
                                                        const short* __restrict__ Bl,
                                                        const float* __restrict__ dinv,
                                                        float* __restrict__ C,
                                                        int M, int K) {
    __shared__ __align__(16) short AhS[BM][LDW];
    __shared__ __align__(16) short AlS[BM][LDW];
    __shared__ __align__(16) short BhS[C_OUT][LDW];
    __shared__ __align__(16) short BlS[C_OUT][LDW];

    const int tid  = threadIdx.x;
    const int lane = tid & 63;
    const int wid  = tid >> 6;            // N quadrant
    const int lr   = lane & 15;
    const int kb   = lane >> 4;
    const int row0 = blockIdx.x * BM;

    f32x4 acc[4][4];
#pragma unroll
    for (int i = 0; i < 4; ++i)
#pragma unroll
        for (int j = 0; j < 4; ++j) acc[i][j] = (f32x4){0.f, 0.f, 0.f, 0.f};

    for (int k0 = 0; k0 < K; k0 += BK) {
#pragma unroll
        for (int it = 0; it < 2; ++it) {
            int flat = tid + it * 256;
            int row = flat >> 3, q = flat & 7;
            float4 v = make_float4(0.f, 0.f, 0.f, 0.f);
            if (row0 + row < M)
                v = *(const float4*)&A[(size_t)(row0 + row) * K + k0 + q * 4];
            short4v hi, lo;
            float f[4] = {v.x, v.y, v.z, v.w};
#pragma unroll
            for (int j = 0; j < 4; ++j) {
                short h = f32_to_bf16_rne(f[j]);
                hi[j] = h;
                lo[j] = f32_to_bf16_rne(f[j] - bf16_to_f32(h));
            }
            *(short4v*)&AhS[row][q * 4] = hi;
            *(short4v*)&AlS[row][q * 4] = lo;
        }
#pragma unroll
        for (int it = 0; it < 4; ++it) {
            int flat = tid + it * 256;
            int row = flat >> 2, g = flat & 3;
            short8 vh = *(const short8*)&Bh[(size_t)row * K + k0 + g * 8];
            short8 vl = *(const short8*)&Bl[(size_t)row * K + k0 + g * 8];
            *(short8*)&BhS[row][g * 8] = vh;
            *(short8*)&BlS[row][g * 8] = vl;
        }
        __syncthreads();

        short8 ah[4], al[4], bh[4], bl[4];
#pragma unroll
        for (int mf = 0; mf < 4; ++mf) {
            int r = mf * 16 + lr;
            ah[mf] = *(const short8*)&AhS[r][kb * 8];
            al[mf] = *(const short8*)&AlS[r][kb * 8];
        }
#pragma unroll
        for (int nf = 0; nf < 4; ++nf) {
            int r = wid * 64 + nf * 16 + lr;
            bh[nf] = *(const short8*)&BhS[r][kb * 8];
            bl[nf] = *(const short8*)&BlS[r][kb * 8];
        }
#pragma unroll
        for (int mf = 0; mf < 4; ++mf)
#pragma unroll
            for (int nf = 0; nf < 4; ++nf) {
                acc[mf][nf] = __builtin_amdgcn_mfma_f32_16x16x32_bf16(ah[mf], bh[nf], acc[mf][nf], 0, 0, 0);
                acc[mf][nf] = __builtin_amdgcn_mfma_f32_16x16x32_bf16(ah[mf], bl[nf], acc[mf][nf], 0, 0, 0);
                acc[mf][nf] = __builtin_amdgcn_mfma_f32_16x16x32_bf16(al[mf], bh[nf], acc[mf][nf], 0, 0, 0);
            }
        __syncthreads();
    }

#pragma unroll
    for (int mf = 0; mf < 4; ++mf) {
#pragma unroll
        for (int r = 0; r < 4; ++r) {
            int grow = row0 + mf * 16 + kb * 4 + r;
            if (grow < M) {
                float dd = dinv[grow];
                float* cp = &C[(size_t)grow * C_OUT + wid * 64 + lr];
#pragma unroll
                for (int nf = 0; nf < 4; ++nf) cp[nf * 16] = acc[mf][nf][r] * dd;
            }
        }
    }
}

// ---------------------------------------------------------------------------
// CSR aggregation, one wave per node.  hs is pre-scaled by dinv[src]:
//   out[d] = dinv[d] * (hs[d] + sum_{s in N(d)} hs[s]) + b    [+ relu]
// Lane l covers channels 4l..4l+3 (64 lanes x float4 = 256 ch, 1KB/row).
// ---------------------------------------------------------------------------
__global__ __launch_bounds__(256) void agg_kernel(const float* __restrict__ hs,
                                                  const int* __restrict__ rowstart,
                                                  const int* __restrict__ srcSorted,
                                                  const float* __restrict__ dinv,
                                                  const float* __restrict__ bias,
                                                  float* __restrict__ out,
                                                  int n, int do_relu) {
    int node = blockIdx.x * 4 + (threadIdx.x >> 6);
    if (node >= n) return;
    int q = threadIdx.x & 63;                      // float4 index within row
    const f32x4* base = (const f32x4*)hs;

    f32x4 acc = base[(size_t)node * 64 + q];       // self-loop term
    int i0 = rowstart[node];
    int i1 = rowstart[node + 1];
    int sNext = (i0 < i1) ? srcSorted[i0] : 0;
    for (int i = i0; i < i1; ++i) {
        int s = sNext;
        if (i + 1 < i1) sNext = srcSorted[i + 1];
        f32x4 v = base[(size_t)s * 64 + q];
        acc += v;
    }
    float dd = dinv[node];
    f32x4 bv = *(const f32x4*)&bias[q << 2];
    f32x4 r = acc * dd + bv;
    if (do_relu) {
        r[0] = fmaxf(r[0], 0.f); r[1] = fmaxf(r[1], 0.f);
        r[2] = fmaxf(r[2], 0.f); r[3] = fmaxf(r[3], 0.f);
    }
    ((f32x4*)out)[(size_t)node * 64 + q] = r;
}

extern "C" void kernel_launch(void* const* d_in, const int* in_sizes, int n_in,
                              void* d_out, int out_size, void* d_ws, size_t ws_size,
                              hipStream_t stream) {
    const float* x  = (const float*)d_in[0];
    const int* ei   = (const int*)d_in[1];
    const float* W1 = (const float*)d_in[2];
    const float* b1 = (const float*)d_in[3];
    const float* W2 = (const float*)d_in[4];
    const float* b2 = (const float*)d_in[5];
    float* out = (float*)d_out;

    const int K1 = 768;
    const int N  = in_sizes[0] / K1;        // 50000
    const int nE = in_sizes[1] / 2;         // 800000
    const int* src = ei;
    const int* dst = ei + nE;

    // workspace layout (16B-aligned chunks)
    char* ws = (char*)d_ws;
    size_t off = 0;
    auto alloc = [&](size_t bytes) { void* p = ws + off; off += (bytes + 255) & ~255ull; return p; };
    float* dinv      = (float*)alloc((size_t)N * 4);
    float* bufA      = (float*)alloc((size_t)N * C_OUT * 4);   // hs1 / hs2
    float* bufB      = (float*)alloc((size_t)N * C_OUT * 4);   // h1
    short* Wh1       = (short*)alloc((size_t)768 * 256 * 2);
    short* Wl1       = (short*)alloc((size_t)768 * 256 * 2);
    short* Wh2       = (short*)alloc((size_t)256 * 256 * 2);
    short* Wl2       = (short*)alloc((size_t)256 * 256 * 2);
    int*   count     = (int*)alloc((size_t)N * 4);
    int*   rowpart   = (int*)alloc((size_t)N * 4);
    int*   rowstart  = (int*)alloc((size_t)(N + 1) * 4);
    int*   cursor    = (int*)alloc((size_t)N * 4);
    int*   bsums     = (int*)alloc(256 * 4);
    int*   srcSorted = (int*)alloc((size_t)nE * 4);

    const int nbN = (N + 255) / 256;        // 196 blocks (fits scan2's 256 cap)
    const int nbE = (nE + 255) / 256;
    const int gemm_blocks = (N + BM - 1) / BM;
    const int agg_blocks = (N + 3) / 4;

    // ---- CSR build + dinv ----
    hipMemsetAsync(count, 0, (size_t)N * 4, stream);
    count_kernel<<<nbE, 256, 0, stream>>>(dst, count, nE);
    scan1_kernel<<<nbN, 256, 0, stream>>>(count, rowpart, bsums, N);
    scan2_kernel<<<1, 256, 0, stream>>>(bsums, nbN);
    scan3_kernel<<<nbN, 256, 0, stream>>>(rowpart, bsums, count, rowstart, cursor, dinv, N, nE);
    fill_kernel<<<nbE, 256, 0, stream>>>(src, dst, cursor, srcSorted, nE);

    // ---- weight split (independent) ----
    wsplit_kernel<<<(768 * 256 + 256 * 256) / 256, 256, 0, stream>>>(W1, W2, Wh1, Wl1, Wh2, Wl2);

    // ---- layer 1 ----
    mfma_gemm_kernel<<<gemm_blocks, 256, 0, stream>>>(x, Wh1, Wl1, dinv, bufA, N, K1);
    agg_kernel<<<agg_blocks, 256, 0, stream>>>(bufA, rowstart, srcSorted, dinv, b1, bufB, N, 1);

    // ---- layer 2 ----
    mfma_gemm_kernel<<<gemm_blocks, 256, 0, stream>>>(bufB, Wh2, Wl2, dinv, bufA, N, C_OUT);
    agg_kernel<<<agg_blocks, 256, 0, stream>>>(bufA, rowstart, srcSorted, dinv, b2, out, N, 0);
}

// Round 4
// 685.262 us; speedup vs baseline: 8.4534x; 1.0288x over previous
//
#include <hip/hip_runtime.h>
#include <hip/hip_bf16.h>
#include <stdint.h>

// ---------------------------------------------------------------------------
// 2-layer GCN on MI355X (gfx950).  Round 4: fragment-order LDS layout in the
// MFMA GEMM (zero-bank-conflict ds_read_b128) + ILP'd CSR aggregation.
//
//   count[d] = in-degree ; dinv = rsqrt(count+1)
//   CSR: rowstart = exscan(count) ; srcSorted bucketed by dst
//   hs1 = (x @ W1) * dinv[row]                       (MFMA GEMM, fused scale)
//   h1  = relu(dinv[d]*(hs1[d] + sum_{s->d} hs1[s]) + b1)   (wave-per-node)
//   hs2 = (h1 @ W2) * dinv[row]
//   out = dinv[d]*(hs2[d] + sum hs2[s]) + b2
// ---------------------------------------------------------------------------

#define C_OUT 256
#define BM 64          // GEMM rows per block
#define BK 32          // GEMM k-step

typedef short  short8  __attribute__((ext_vector_type(8)));
typedef short  short4v __attribute__((ext_vector_type(4)));
typedef float  f32x4   __attribute__((ext_vector_type(4)));

static __device__ __forceinline__ short f32_to_bf16_rne(float f) {
    uint32_t u = __builtin_bit_cast(uint32_t, f);
    uint32_t r = 0x7FFFu + ((u >> 16) & 1u);
    return (short)((u + r) >> 16);
}
static __device__ __forceinline__ float bf16_to_f32(short s) {
    uint32_t u = ((uint32_t)(uint16_t)s) << 16;
    return __builtin_bit_cast(float, u);
}

// --------------------------- CSR build ------------------------------------
__global__ __launch_bounds__(256) void count_kernel(const int* __restrict__ dst,
                                                    int* __restrict__ count, int nE) {
    int e = blockIdx.x * blockDim.x + threadIdx.x;
    if (e < nE) atomicAdd(&count[dst[e]], 1);
}

__global__ __launch_bounds__(256) void scan1_kernel(const int* __restrict__ count,
                                                    int* __restrict__ rowpart,
                                                    int* __restrict__ bsums, int n) {
    __shared__ int tmp[256];
    int t = threadIdx.x;
    int i = blockIdx.x * 256 + t;
    int v = (i < n) ? count[i] : 0;
    tmp[t] = v;
    __syncthreads();
    for (int off = 1; off < 256; off <<= 1) {
        int u = 0;
        if (t >= off) u = tmp[t - off];
        __syncthreads();
        if (t >= off) tmp[t] += u;
        __syncthreads();
    }
    if (i < n) rowpart[i] = tmp[t] - v;          // exclusive
    if (t == 255) bsums[blockIdx.x] = tmp[255];  // block total
}

__global__ __launch_bounds__(256) void scan2_kernel(int* __restrict__ bsums, int nb) {
    __shared__ int tmp[256];
    int t = threadIdx.x;
    int v = (t < nb) ? bsums[t] : 0;
    tmp[t] = v;
    __syncthreads();
    for (int off = 1; off < 256; off <<= 1) {
        int u = 0;
        if (t >= off) u = tmp[t - off];
        __syncthreads();
        if (t >= off) tmp[t] += u;
        __syncthreads();
    }
    if (t < nb) bsums[t] = tmp[t] - v;           // exclusive, in-place
}

__global__ __launch_bounds__(256) void scan3_kernel(const int* __restrict__ rowpart,
                                                    const int* __restrict__ bsums,
                                                    const int* __restrict__ count,
                                                    int* __restrict__ rowstart,
                                                    int* __restrict__ cursor,
                                                    float* __restrict__ dinv,
                                                    int n, int nE) {
    int i = blockIdx.x * 256 + threadIdx.x;
    if (i < n) {
        int r = rowpart[i] + bsums[blockIdx.x];
        rowstart[i] = r;
        cursor[i] = r;
        dinv[i] = rsqrtf((float)count[i] + 1.0f);
    }
    if (i == 0) rowstart[n] = nE;
}

__global__ __launch_bounds__(256) void fill_kernel(const int* __restrict__ src,
                                                   const int* __restrict__ dst,
                                                   int* __restrict__ cursor,
                                                   int* __restrict__ srcSorted, int nE) {
    int e = blockIdx.x * blockDim.x + threadIdx.x;
    if (e < nE) {
        int p = atomicAdd(&cursor[dst[e]], 1);
        srcSorted[p] = src[e];
    }
}

// ------------------- weight split + transpose (once per launch) ------------
__global__ __launch_bounds__(256) void wsplit_kernel(const float* __restrict__ W1,
                                                     const float* __restrict__ W2,
                                                     short* __restrict__ Wh1, short* __restrict__ Wl1,
                                                     short* __restrict__ Wh2, short* __restrict__ Wl2) {
    int i = blockIdx.x * 256 + threadIdx.x;
    if (i < 768 * 256) {
        int k = i >> 8, n = i & 255;
        float v = W1[i];
        short h = f32_to_bf16_rne(v);
        short l = f32_to_bf16_rne(v - bf16_to_f32(h));
        Wh1[n * 768 + k] = h;
        Wl1[n * 768 + k] = l;
    } else {
        int j = i - 768 * 256;
        int k = j >> 8, n = j & 255;
        float v = W2[j];
        short h = f32_to_bf16_rne(v);
        short l = f32_to_bf16_rne(v - bf16_to_f32(h));
        Wh2[n * 256 + k] = h;
        Wl2[n * 256 + k] = l;
    }
}

// ---------------------------------------------------------------------------
// MFMA GEMM with fused row-scale:  C[M,256] = (A[M,K] @ W[K,256]) * dinv[row]
// acc += Ah*Bh + Ah*Bl + Al*Bh   (bf16x3 split product)
// Block: 256 threads = 4 waves; tile 64(M) x 256(N); wave tile 64x64.
//
// LDS is FRAGMENT-ORDER: the short8 fragment consumed by wave-lane l of
// fragment-block f sits at base + (f*64 + l)*16 bytes.  Every ds_read_b128
// is a wave-contiguous 1024B read -> zero bank conflicts by construction.
//   A slot:  f = mf (row>>4);        l = kb*16 + (row&15), elems = k&7
//   B slot:  f = row>>4 (=wid*4+nf); l = kb*16 + (row&15)
// ---------------------------------------------------------------------------
__global__ __launch_bounds__(256) void mfma_gemm_kernel(const float* __restrict__ A,
                                                        const short* __restrict__ Bh,
                                                        const short* __restrict__ Bl,
                                                        const float* __restrict__ dinv,
                                                        float* __restrict__ C,
                                                        int M, int K) {
    __shared__ __align__(16) short AhS[BM * BK];        // 4 KB
    __shared__ __align__(16) short AlS[BM * BK];        // 4 KB
    __shared__ __align__(16) short BhS[C_OUT * BK];     // 16 KB
    __shared__ __align__(16) short BlS[C_OUT * BK];     // 16 KB

    const int tid  = threadIdx.x;
    const int lane = tid & 63;
    const int wid  = tid >> 6;            // N quadrant
    const int row0 = blockIdx.x * BM;

    // staging maps (4 lanes per row -> 64B coalesced global segments)
    const int a_row = tid >> 2;                    // 0..63
    const int b_kb  = tid & 3;

    f32x4 acc[4][4];
#pragma unroll
    for (int i = 0; i < 4; ++i)
#pragma unroll
        for (int j = 0; j < 4; ++j) acc[i][j] = (f32x4){0.f, 0.f, 0.f, 0.f};

    const bool arow_ok = (row0 + a_row) < M;
    const float* Aptr = A + (size_t)(row0 + a_row) * K;

    for (int k0 = 0; k0 < K; k0 += BK) {
        // ---- stage A: [64][32] fp32 -> split hi/lo bf16, fragment order ----
#pragma unroll
        for (int it = 0; it < 2; ++it) {
            int q = (tid & 3) + it * 4;            // float4 index 0..7
            float4 v = make_float4(0.f, 0.f, 0.f, 0.f);
            if (arow_ok) v = *(const float4*)(Aptr + k0 + q * 4);
            short4v hi, lo;
            float f[4] = {v.x, v.y, v.z, v.w};
#pragma unroll
            for (int j = 0; j < 4; ++j) {
                short h = f32_to_bf16_rne(f[j]);
                hi[j] = h;
                lo[j] = f32_to_bf16_rne(f[j] - bf16_to_f32(h));
            }
            int kb = q >> 1, e0 = (q & 1) * 4;
            int s = ((a_row >> 4) * 64 + kb * 16 + (a_row & 15)) * 8 + e0;
            *(short4v*)&AhS[s] = hi;
            *(short4v*)&AlS[s] = lo;
        }
        // ---- stage B: [256][32] bf16, fragment order ----
#pragma unroll
        for (int it = 0; it < 4; ++it) {
            int row = (tid >> 2) + it * 64;        // 0..255
            const size_t g = (size_t)row * K + k0 + b_kb * 8;
            short8 vh = *(const short8*)&Bh[g];
            short8 vl = *(const short8*)&Bl[g];
            int s = ((row >> 4) * 64 + b_kb * 16 + (row & 15)) * 8;
            *(short8*)&BhS[s] = vh;
            *(short8*)&BlS[s] = vl;
        }
        __syncthreads();

        // ---- fragments (wave-contiguous reads) + MFMA ----
        short8 ah[4], al[4], bh[4], bl[4];
#pragma unroll
        for (int mf = 0; mf < 4; ++mf) {
            ah[mf] = *(const short8*)&AhS[(mf * 64 + lane) * 8];
            al[mf] = *(const short8*)&AlS[(mf * 64 + lane) * 8];
        }
#pragma unroll
        for (int nf = 0; nf < 4; ++nf) {
            bh[nf] = *(const short8*)&BhS[((wid * 4 + nf) * 64 + lane) * 8];
            bl[nf] = *(const short8*)&BlS[((wid * 4 + nf) * 64 + lane) * 8];
        }
#pragma unroll
        for (int mf = 0; mf < 4; ++mf)
#pragma unroll
            for (int nf = 0; nf < 4; ++nf) {
                acc[mf][nf] = __builtin_amdgcn_mfma_f32_16x16x32_bf16(ah[mf], bh[nf], acc[mf][nf], 0, 0, 0);
                acc[mf][nf] = __builtin_amdgcn_mfma_f32_16x16x32_bf16(ah[mf], bl[nf], acc[mf][nf], 0, 0, 0);
                acc[mf][nf] = __builtin_amdgcn_mfma_f32_16x16x32_bf16(al[mf], bh[nf], acc[mf][nf], 0, 0, 0);
            }
        __syncthreads();
    }

    // ---- C write: col = lane&15, row = (lane>>4)*4 + r  [m89/m91-verified] ----
    const int lr = lane & 15;
    const int kb = lane >> 4;
#pragma unroll
    for (int mf = 0; mf < 4; ++mf) {
#pragma unroll
        for (int r = 0; r < 4; ++r) {
            int grow = row0 + mf * 16 + kb * 4 + r;
            if (grow < M) {
                float dd = dinv[grow];
                float* cp = &C[(size_t)grow * C_OUT + wid * 64 + lr];
#pragma unroll
                for (int nf = 0; nf < 4; ++nf) cp[nf * 16] = acc[mf][nf][r] * dd;
            }
        }
    }
}

// ---------------------------------------------------------------------------
// CSR aggregation, one wave per node, 2-edge unroll w/ dual accumulators.
//   out[d] = dinv[d] * (hs[d] + sum_{s in N(d)} hs[s]) + b    [+ relu]
// ---------------------------------------------------------------------------
__global__ __launch_bounds__(256) void agg_kernel(const float* __restrict__ hs,
                                                  const int* __restrict__ rowstart,
                                                  const int* __restrict__ srcSorted,
                                                  const float* __restrict__ dinv,
                                                  const float* __restrict__ bias,
                                                  float* __restrict__ out,
                                                  int n, int do_relu) {
    int node = blockIdx.x * 4 + (threadIdx.x >> 6);
    if (node >= n) return;
    int q = threadIdx.x & 63;                      // float4 index within row
    const f32x4* base = (const f32x4*)hs;

    f32x4 acc0 = base[(size_t)node * 64 + q];      // self-loop term
    f32x4 acc1 = (f32x4){0.f, 0.f, 0.f, 0.f};
    int i0 = rowstart[node];
    int i1 = rowstart[node + 1];
    int i = i0;
    for (; i + 1 < i1; i += 2) {
        int s0 = srcSorted[i];
        int s1 = srcSorted[i + 1];
        f32x4 v0 = base[(size_t)s0 * 64 + q];
        f32x4 v1 = base[(size_t)s1 * 64 + q];
        acc0 += v0;
        acc1 += v1;
    }
    if (i < i1) acc0 += base[(size_t)srcSorted[i] * 64 + q];

    float dd = dinv[node];
    f32x4 bv = *(const f32x4*)&bias[q << 2];
    f32x4 r = (acc0 + acc1) * dd + bv;
    if (do_relu) {
        r[0] = fmaxf(r[0], 0.f); r[1] = fmaxf(r[1], 0.f);
        r[2] = fmaxf(r[2], 0.f); r[3] = fmaxf(r[3], 0.f);
    }
    ((f32x4*)out)[(size_t)node * 64 + q] = r;
}

extern "C" void kernel_launch(void* const* d_in, const int* in_sizes, int n_in,
                              void* d_out, int out_size, void* d_ws, size_t ws_size,
                              hipStream_t stream) {
    const float* x  = (const float*)d_in[0];
    const int* ei   = (const int*)d_in[1];
    const float* W1 = (const float*)d_in[2];
    const float* b1 = (const float*)d_in[3];
    const float* W2 = (const float*)d_in[4];
    const float* b2 = (const float*)d_in[5];
    float* out = (float*)d_out;

    const int K1 = 768;
    const int N  = in_sizes[0] / K1;        // 50000
    const int nE = in_sizes[1] / 2;         // 800000
    const int* src = ei;
    const int* dst = ei + nE;

    // workspace layout (256B-aligned chunks)
    char* ws = (char*)d_ws;
    size_t off = 0;
    auto alloc = [&](size_t bytes) { void* p = ws + off; off += (bytes + 255) & ~255ull; return p; };
    float* dinv      = (float*)alloc((size_t)N * 4);
    float* bufA      = (float*)alloc((size_t)N * C_OUT * 4);   // hs1 / hs2
    float* bufB      = (float*)alloc((size_t)N * C_OUT * 4);   // h1
    short* Wh1       = (short*)alloc((size_t)768 * 256 * 2);
    short* Wl1       = (short*)alloc((size_t)768 * 256 * 2);
    short* Wh2       = (short*)alloc((size_t)256 * 256 * 2);
    short* Wl2       = (short*)alloc((size_t)256 * 256 * 2);
    int*   count     = (int*)alloc((size_t)N * 4);
    int*   rowpart   = (int*)alloc((size_t)N * 4);
    int*   rowstart  = (int*)alloc((size_t)(N + 1) * 4);
    int*   cursor    = (int*)alloc((size_t)N * 4);
    int*   bsums     = (int*)alloc(256 * 4);
    int*   srcSorted = (int*)alloc((size_t)nE * 4);

    const int nbN = (N + 255) / 256;        // 196 blocks (fits scan2's 256 cap)
    const int nbE = (nE + 255) / 256;
    const int gemm_blocks = (N + BM - 1) / BM;
    const int agg_blocks = (N + 3) / 4;

    // ---- CSR build + dinv ----
    hipMemsetAsync(count, 0, (size_t)N * 4, stream);
    count_kernel<<<nbE, 256, 0, stream>>>(dst, count, nE);
    scan1_kernel<<<nbN, 256, 0, stream>>>(count, rowpart, bsums, N);
    scan2_kernel<<<1, 256, 0, stream>>>(bsums, nbN);
    scan3_kernel<<<nbN, 256, 0, stream>>>(rowpart, bsums, count, rowstart, cursor, dinv, N, nE);
    fill_kernel<<<nbE, 256, 0, stream>>>(src, dst, cursor, srcSorted, nE);

    // ---- weight split ----
    wsplit_kernel<<<(768 * 256 + 256 * 256) / 256, 256, 0, stream>>>(W1, W2, Wh1, Wl1, Wh2, Wl2);

    // ---- layer 1 ----
    mfma_gemm_kernel<<<gemm_blocks, 256, 0, stream>>>(x, Wh1, Wl1, dinv, bufA, N, K1);
    agg_kernel<<<agg_blocks, 256, 0, stream>>>(bufA, rowstart, srcSorted, dinv, b1, bufB, N, 1);

    // ---- layer 2 ----
    mfma_gemm_kernel<<<gemm_blocks, 256, 0, stream>>>(bufB, Wh2, Wl2, dinv, bufA, N, C_OUT);
    agg_kernel<<<agg_blocks, 256, 0, stream>>>(bufA, rowstart, srcSorted, dinv, b2, out, N, 0);
}

// Round 5
// 660.309 us; speedup vs baseline: 8.7729x; 1.0378x over previous
//
#include <hip/hip_runtime.h>
#include <hip/hip_bf16.h>
#include <stdint.h>

// ---------------------------------------------------------------------------
// 2-layer GCN on MI355X (gfx950).  Round 5: B fragments pre-swizzled in GLOBAL
// memory (fragment order) -> loaded straight to VGPRs (no B LDS, no write
// conflicts).  LDS holds only the A tile (8 KB).  CSR gather aggregation.
//
//   count[d] = in-degree ; dinv = rsqrt(count+1)
//   CSR: rowstart = exscan(count) ; srcSorted bucketed by dst
//   hs1 = (x @ W1) * dinv[row]                       (MFMA GEMM, fused scale)
//   h1  = relu(dinv[d]*(hs1[d] + sum_{s->d} hs1[s]) + b1)   (wave-per-node)
//   hs2 = (h1 @ W2) * dinv[row]
//   out = dinv[d]*(hs2[d] + sum hs2[s]) + b2
// ---------------------------------------------------------------------------

#define C_OUT 256
#define BM 64          // GEMM rows per block
#define BK 32          // GEMM k-step

typedef short  short8  __attribute__((ext_vector_type(8)));
typedef short  short4v __attribute__((ext_vector_type(4)));
typedef float  f32x4   __attribute__((ext_vector_type(4)));

static __device__ __forceinline__ short f32_to_bf16_rne(float f) {
    uint32_t u = __builtin_bit_cast(uint32_t, f);
    uint32_t r = 0x7FFFu + ((u >> 16) & 1u);
    return (short)((u + r) >> 16);
}
static __device__ __forceinline__ float bf16_to_f32(short s) {
    uint32_t u = ((uint32_t)(uint16_t)s) << 16;
    return __builtin_bit_cast(float, u);
}

// --------------------------- CSR build ------------------------------------
__global__ __launch_bounds__(256) void count_kernel(const int* __restrict__ dst,
                                                    int* __restrict__ count, int nE) {
    int e = blockIdx.x * blockDim.x + threadIdx.x;
    if (e < nE) atomicAdd(&count[dst[e]], 1);
}

__global__ __launch_bounds__(256) void scan1_kernel(const int* __restrict__ count,
                                                    int* __restrict__ rowpart,
                                                    int* __restrict__ bsums, int n) {
    __shared__ int tmp[256];
    int t = threadIdx.x;
    int i = blockIdx.x * 256 + t;
    int v = (i < n) ? count[i] : 0;
    tmp[t] = v;
    __syncthreads();
    for (int off = 1; off < 256; off <<= 1) {
        int u = 0;
        if (t >= off) u = tmp[t - off];
        __syncthreads();
        if (t >= off) tmp[t] += u;
        __syncthreads();
    }
    if (i < n) rowpart[i] = tmp[t] - v;          // exclusive
    if (t == 255) bsums[blockIdx.x] = tmp[255];  // block total
}

__global__ __launch_bounds__(256) void scan2_kernel(int* __restrict__ bsums, int nb) {
    __shared__ int tmp[256];
    int t = threadIdx.x;
    int v = (t < nb) ? bsums[t] : 0;
    tmp[t] = v;
    __syncthreads();
    for (int off = 1; off < 256; off <<= 1) {
        int u = 0;
        if (t >= off) u = tmp[t - off];
        __syncthreads();
        if (t >= off) tmp[t] += u;
        __syncthreads();
    }
    if (t < nb) bsums[t] = tmp[t] - v;           // exclusive, in-place
}

__global__ __launch_bounds__(256) void scan3_kernel(const int* __restrict__ rowpart,
                                                    const int* __restrict__ bsums,
                                                    const int* __restrict__ count,
                                                    int* __restrict__ rowstart,
                                                    int* __restrict__ cursor,
                                                    float* __restrict__ dinv,
                                                    int n, int nE) {
    int i = blockIdx.x * 256 + threadIdx.x;
    if (i < n) {
        int r = rowpart[i] + bsums[blockIdx.x];
        rowstart[i] = r;
        cursor[i] = r;
        dinv[i] = rsqrtf((float)count[i] + 1.0f);
    }
    if (i == 0) rowstart[n] = nE;
}

__global__ __launch_bounds__(256) void fill_kernel(const int* __restrict__ src,
                                                   const int* __restrict__ dst,
                                                   int* __restrict__ cursor,
                                                   int* __restrict__ srcSorted, int nE) {
    int e = blockIdx.x * blockDim.x + threadIdx.x;
    if (e < nE) {
        int p = atomicAdd(&cursor[dst[e]], 1);
        srcSorted[p] = src[e];
    }
}

// ---------------------------------------------------------------------------
// Weight split into FRAGMENT-ORDER global layout.
// Wf element index for (kk, f, l, e) = ((kk*16 + f)*64 + l)*8 + e
//   holds W[kk*32 + (l>>4)*8 + e][f*16 + (l&15)]   (W row-major [K][256])
// One thread per (kk,f,l): 8 column-strided reads, one short8 store per plane.
// ---------------------------------------------------------------------------
__global__ __launch_bounds__(256) void wsplit_frag_kernel(const float* __restrict__ W,
                                                          short* __restrict__ Wh,
                                                          short* __restrict__ Wl,
                                                          int K) {
    int t = blockIdx.x * 256 + threadIdx.x;          // (K/32)*1024 threads
    if (t >= (K >> 5) * 1024) return;
    int l = t & 63;
    int f = (t >> 6) & 15;
    int kk = t >> 10;
    int n = f * 16 + (l & 15);
    int kbase = kk * 32 + ((l >> 4) << 3);
    short8 hi, lo;
#pragma unroll
    for (int e = 0; e < 8; ++e) {
        float v = W[(size_t)(kbase + e) * 256 + n];
        short h = f32_to_bf16_rne(v);
        hi[e] = h;
        lo[e] = f32_to_bf16_rne(v - bf16_to_f32(h));
    }
    *(short8*)&Wh[(size_t)t * 8] = hi;
    *(short8*)&Wl[(size_t)t * 8] = lo;
}

// ---------------------------------------------------------------------------
// MFMA GEMM with fused row-scale:  C[M,256] = (A[M,K] @ W[K,256]) * dinv[row]
// acc += Ah*Bh + Ah*Bl + Al*Bh   (bf16x3 split product)
// Block: 256 threads = 4 waves; tile 64(M) x 256(N); wave tile 64x64.
// B fragments: DIRECT global->VGPR from fragment-order W (L2-resident, no
// cross-wave sharing -> LDS not needed).  A tile: split hi/lo in LDS (8 KB),
// fragment-order so frag reads are wave-contiguous 1KB ds_read_b128.
// ---------------------------------------------------------------------------
__global__ __launch_bounds__(256) void mfma_gemm_kernel(const float* __restrict__ A,
                                                        const short* __restrict__ Bhf,
                                                        const short* __restrict__ Blf,
                                                        const float* __restrict__ dinv,
                                                        float* __restrict__ C,
                                                        int M, int K) {
    __shared__ __align__(16) short AhS[BM * BK];        // 4 KB
    __shared__ __align__(16) short AlS[BM * BK];        // 4 KB

    const int tid  = threadIdx.x;
    const int lane = tid & 63;
    const int wid  = tid >> 6;            // N quadrant
    const int row0 = blockIdx.x * BM;

    const int a_row = tid >> 2;           // staging: 4 lanes per row
    const bool arow_ok = (row0 + a_row) < M;
    const float* Aptr = A + (size_t)(row0 + a_row) * K;

    f32x4 acc[4][4];
#pragma unroll
    for (int i = 0; i < 4; ++i)
#pragma unroll
        for (int j = 0; j < 4; ++j) acc[i][j] = (f32x4){0.f, 0.f, 0.f, 0.f};

    const int nk = K >> 5;
    for (int kk = 0; kk < nk; ++kk) {
        // ---- B fragments straight to regs (L2-resident; latency hides under A) ----
        short8 bh[4], bl[4];
#pragma unroll
        for (int nf = 0; nf < 4; ++nf) {
            size_t off = ((size_t)(kk * 16 + wid * 4 + nf) * 64 + lane) * 8;
            bh[nf] = *(const short8*)&Bhf[off];
            bl[nf] = *(const short8*)&Blf[off];
        }
        // ---- stage A: [64][32] fp32 -> split hi/lo bf16, fragment order ----
#pragma unroll
        for (int it = 0; it < 2; ++it) {
            int q = (tid & 3) + it * 4;            // float4 index 0..7
            float4 v = make_float4(0.f, 0.f, 0.f, 0.f);
            if (arow_ok) v = *(const float4*)(Aptr + kk * 32 + q * 4);
            short4v hi, lo;
            float f[4] = {v.x, v.y, v.z, v.w};
#pragma unroll
            for (int j = 0; j < 4; ++j) {
                short h = f32_to_bf16_rne(f[j]);
                hi[j] = h;
                lo[j] = f32_to_bf16_rne(f[j] - bf16_to_f32(h));
            }
            int kb = q >> 1, e0 = (q & 1) * 4;
            int s = ((a_row >> 4) * 64 + kb * 16 + (a_row & 15)) * 8 + e0;
            *(short4v*)&AhS[s] = hi;
            *(short4v*)&AlS[s] = lo;
        }
        __syncthreads();

        // ---- A fragments (wave-contiguous reads) + MFMA ----
        short8 ah[4], al[4];
#pragma unroll
        for (int mf = 0; mf < 4; ++mf) {
            ah[mf] = *(const short8*)&AhS[(mf * 64 + lane) * 8];
            al[mf] = *(const short8*)&AlS[(mf * 64 + lane) * 8];
        }
#pragma unroll
        for (int mf = 0; mf < 4; ++mf)
#pragma unroll
            for (int nf = 0; nf < 4; ++nf) {
                acc[mf][nf] = __builtin_amdgcn_mfma_f32_16x16x32_bf16(ah[mf], bh[nf], acc[mf][nf], 0, 0, 0);
                acc[mf][nf] = __builtin_amdgcn_mfma_f32_16x16x32_bf16(ah[mf], bl[nf], acc[mf][nf], 0, 0, 0);
                acc[mf][nf] = __builtin_amdgcn_mfma_f32_16x16x32_bf16(al[mf], bh[nf], acc[mf][nf], 0, 0, 0);
            }
        __syncthreads();
    }

    // ---- C write: col = lane&15, row = (lane>>4)*4 + r ----
    const int lr = lane & 15;
    const int kb = lane >> 4;
#pragma unroll
    for (int mf = 0; mf < 4; ++mf) {
#pragma unroll
        for (int r = 0; r < 4; ++r) {
            int grow = row0 + mf * 16 + kb * 4 + r;
            if (grow < M) {
                float dd = dinv[grow];
                float* cp = &C[(size_t)grow * C_OUT + wid * 64 + lr];
#pragma unroll
                for (int nf = 0; nf < 4; ++nf) cp[nf * 16] = acc[mf][nf][r] * dd;
            }
        }
    }
}

// ---------------------------------------------------------------------------
// CSR aggregation, one wave per node, 4-deep unroll (4 independent gathers
// in flight).   out[d] = dinv[d]*(hs[d] + sum_{s in N(d)} hs[s]) + b  [+relu]
// ---------------------------------------------------------------------------
__global__ __launch_bounds__(256) void agg_kernel(const float* __restrict__ hs,
                                                  const int* __restrict__ rowstart,
                                                  const int* __restrict__ srcSorted,
                                                  const float* __restrict__ dinv,
                                                  const float* __restrict__ bias,
                                                  float* __restrict__ out,
                                                  int n, int do_relu) {
    int node = blockIdx.x * 4 + (threadIdx.x >> 6);
    if (node >= n) return;
    int q = threadIdx.x & 63;                      // float4 index within row
    const f32x4* base = (const f32x4*)hs;

    f32x4 acc0 = base[(size_t)node * 64 + q];      // self-loop term
    f32x4 acc1 = (f32x4){0.f, 0.f, 0.f, 0.f};
    f32x4 acc2 = (f32x4){0.f, 0.f, 0.f, 0.f};
    f32x4 acc3 = (f32x4){0.f, 0.f, 0.f, 0.f};
    int i0 = rowstart[node];
    int i1 = rowstart[node + 1];
    int i = i0;
    for (; i + 3 < i1; i += 4) {
        int s0 = srcSorted[i];
        int s1 = srcSorted[i + 1];
        int s2 = srcSorted[i + 2];
        int s3 = srcSorted[i + 3];
        acc0 += base[(size_t)s0 * 64 + q];
        acc1 += base[(size_t)s1 * 64 + q];
        acc2 += base[(size_t)s2 * 64 + q];
        acc3 += base[(size_t)s3 * 64 + q];
    }
    for (; i < i1; ++i) acc0 += base[(size_t)srcSorted[i] * 64 + q];

    float dd = dinv[node];
    f32x4 bv = *(const f32x4*)&bias[q << 2];
    f32x4 r = ((acc0 + acc1) + (acc2 + acc3)) * dd + bv;
    if (do_relu) {
        r[0] = fmaxf(r[0], 0.f); r[1] = fmaxf(r[1], 0.f);
        r[2] = fmaxf(r[2], 0.f); r[3] = fmaxf(r[3], 0.f);
    }
    ((f32x4*)out)[(size_t)node * 64 + q] = r;
}

extern "C" void kernel_launch(void* const* d_in, const int* in_sizes, int n_in,
                              void* d_out, int out_size, void* d_ws, size_t ws_size,
                              hipStream_t stream) {
    const float* x  = (const float*)d_in[0];
    const int* ei   = (const int*)d_in[1];
    const float* W1 = (const float*)d_in[2];
    const float* b1 = (const float*)d_in[3];
    const float* W2 = (const float*)d_in[4];
    const float* b2 = (const float*)d_in[5];
    float* out = (float*)d_out;

    const int K1 = 768;
    const int N  = in_sizes[0] / K1;        // 50000
    const int nE = in_sizes[1] / 2;         // 800000
    const int* src = ei;
    const int* dst = ei + nE;

    // workspace layout (256B-aligned chunks)
    char* ws = (char*)d_ws;
    size_t off = 0;
    auto alloc = [&](size_t bytes) { void* p = ws + off; off += (bytes + 255) & ~255ull; return p; };
    float* dinv      = (float*)alloc((size_t)N * 4);
    float* bufA      = (float*)alloc((size_t)N * C_OUT * 4);   // hs1 / hs2
    float* bufB      = (float*)alloc((size_t)N * C_OUT * 4);   // h1
    short* Wh1       = (short*)alloc((size_t)768 * 256 * 2);   // fragment order
    short* Wl1       = (short*)alloc((size_t)768 * 256 * 2);
    short* Wh2       = (short*)alloc((size_t)256 * 256 * 2);
    short* Wl2       = (short*)alloc((size_t)256 * 256 * 2);
    int*   count     = (int*)alloc((size_t)N * 4);
    int*   rowpart   = (int*)alloc((size_t)N * 4);
    int*   rowstart  = (int*)alloc((size_t)(N + 1) * 4);
    int*   cursor    = (int*)alloc((size_t)N * 4);
    int*   bsums     = (int*)alloc(256 * 4);
    int*   srcSorted = (int*)alloc((size_t)nE * 4);

    const int nbN = (N + 255) / 256;        // 196 blocks (fits scan2's 256 cap)
    const int nbE = (nE + 255) / 256;
    const int gemm_blocks = (N + BM - 1) / BM;
    const int agg_blocks = (N + 3) / 4;

    // ---- CSR build + dinv ----
    hipMemsetAsync(count, 0, (size_t)N * 4, stream);
    count_kernel<<<nbE, 256, 0, stream>>>(dst, count, nE);
    scan1_kernel<<<nbN, 256, 0, stream>>>(count, rowpart, bsums, N);
    scan2_kernel<<<1, 256, 0, stream>>>(bsums, nbN);
    scan3_kernel<<<nbN, 256, 0, stream>>>(rowpart, bsums, count, rowstart, cursor, dinv, N, nE);
    fill_kernel<<<nbE, 256, 0, stream>>>(src, dst, cursor, srcSorted, nE);

    // ---- weight split into fragment order ----
    wsplit_frag_kernel<<<(768 / 32 * 1024 + 255) / 256, 256, 0, stream>>>(W1, Wh1, Wl1, 768);
    wsplit_frag_kernel<<<(256 / 32 * 1024 + 255) / 256, 256, 0, stream>>>(W2, Wh2, Wl2, 256);

    // ---- layer 1 ----
    mfma_gemm_kernel<<<gemm_blocks, 256, 0, stream>>>(x, Wh1, Wl1, dinv, bufA, N, K1);
    agg_kernel<<<agg_blocks, 256, 0, stream>>>(bufA, rowstart, srcSorted, dinv, b1, bufB, N, 1);

    // ---- layer 2 ----
    mfma_gemm_kernel<<<gemm_blocks, 256, 0, stream>>>(bufB, Wh2, Wl2, dinv, bufA, N, C_OUT);
    agg_kernel<<<agg_blocks, 256, 0, stream>>>(bufA, rowstart, srcSorted, dinv, b2, out, N, 0);
}

// Round 8
// 649.093 us; speedup vs baseline: 8.9245x; 1.0173x over previous
//
#include <hip/hip_runtime.h>
#include <hip/hip_bf16.h>
#include <stdint.h>

// ---------------------------------------------------------------------------
// 2-layer GCN on MI355X (gfx950).  Round 8: Round-5's VERIFIED two-barrier
// GEMM skeleton + register-only A prefetch (issued one K-step early; the only
// cross-barrier in-flight ops are reg-destination global loads -> no LDS
// hazard).  Round 6's single-barrier/double-buffer variant corrupted on warm
// replays and is abandoned.
//
//   count[d] = in-degree ; dinv = rsqrt(count+1)
//   CSR: rowstart = exscan(count) ; srcSorted bucketed by dst
//   hs1 = (x @ W1) * dinv[row]                       (MFMA GEMM, fused scale)
//   h1  = relu(dinv[d]*(hs1[d] + sum_{s->d} hs1[s]) + b1)   (wave-per-node)
//   hs2 = (h1 @ W2) * dinv[row]
//   out = dinv[d]*(hs2[d] + sum hs2[s]) + b2
// ---------------------------------------------------------------------------

#define C_OUT 256
#define BM 64          // GEMM rows per block
#define BK 32          // GEMM k-step
#define BSTEP (16 * 64 * 8)   // shorts per K-step in fragment-order W

typedef short  short8  __attribute__((ext_vector_type(8)));
typedef short  short4v __attribute__((ext_vector_type(4)));
typedef float  f32x4   __attribute__((ext_vector_type(4)));

static __device__ __forceinline__ short f32_to_bf16_rne(float f) {
    uint32_t u = __builtin_bit_cast(uint32_t, f);
    uint32_t r = 0x7FFFu + ((u >> 16) & 1u);
    return (short)((u + r) >> 16);
}
static __device__ __forceinline__ float bf16_to_f32(short s) {
    uint32_t u = ((uint32_t)(uint16_t)s) << 16;
    return __builtin_bit_cast(float, u);
}
static __device__ __forceinline__ void cvt_split4(float4 v, short4v& hi, short4v& lo) {
    float f[4] = {v.x, v.y, v.z, v.w};
#pragma unroll
    for (int j = 0; j < 4; ++j) {
        short h = f32_to_bf16_rne(f[j]);
        hi[j] = h;
        lo[j] = f32_to_bf16_rne(f[j] - bf16_to_f32(h));
    }
}

// --------------------------- CSR build ------------------------------------
__global__ __launch_bounds__(256) void count_kernel(const int* __restrict__ dst,
                                                    int* __restrict__ count, int nE) {
    int e = blockIdx.x * blockDim.x + threadIdx.x;
    if (e < nE) atomicAdd(&count[dst[e]], 1);
}

__global__ __launch_bounds__(256) void scan1_kernel(const int* __restrict__ count,
                                                    int* __restrict__ rowpart,
                                                    int* __restrict__ bsums, int n) {
    __shared__ int tmp[256];
    int t = threadIdx.x;
    int i = blockIdx.x * 256 + t;
    int v = (i < n) ? count[i] : 0;
    tmp[t] = v;
    __syncthreads();
    for (int off = 1; off < 256; off <<= 1) {
        int u = 0;
        if (t >= off) u = tmp[t - off];
        __syncthreads();
        if (t >= off) tmp[t] += u;
        __syncthreads();
    }
    if (i < n) rowpart[i] = tmp[t] - v;          // exclusive
    if (t == 255) bsums[blockIdx.x] = tmp[255];  // block total
}

__global__ __launch_bounds__(256) void scan2_kernel(int* __restrict__ bsums, int nb) {
    __shared__ int tmp[256];
    int t = threadIdx.x;
    int v = (t < nb) ? bsums[t] : 0;
    tmp[t] = v;
    __syncthreads();
    for (int off = 1; off < 256; off <<= 1) {
        int u = 0;
        if (t >= off) u = tmp[t - off];
        __syncthreads();
        if (t >= off) tmp[t] += u;
        __syncthreads();
    }
    if (t < nb) bsums[t] = tmp[t] - v;           // exclusive, in-place
}

__global__ __launch_bounds__(256) void scan3_kernel(const int* __restrict__ rowpart,
                                                    const int* __restrict__ bsums,
                                                    const int* __restrict__ count,
                                                    int* __restrict__ rowstart,
                                                    int* __restrict__ cursor,
                                                    float* __restrict__ dinv,
                                                    int n, int nE) {
    int i = blockIdx.x * 256 + threadIdx.x;
    if (i < n) {
        int r = rowpart[i] + bsums[blockIdx.x];
        rowstart[i] = r;
        cursor[i] = r;
        dinv[i] = rsqrtf((float)count[i] + 1.0f);
    }
    if (i == 0) rowstart[n] = nE;
}

__global__ __launch_bounds__(256) void fill_kernel(const int* __restrict__ src,
                                                   const int* __restrict__ dst,
                                                   int* __restrict__ cursor,
                                                   int* __restrict__ srcSorted, int nE) {
    int e = blockIdx.x * blockDim.x + threadIdx.x;
    if (e < nE) {
        int p = atomicAdd(&cursor[dst[e]], 1);
        srcSorted[p] = src[e];
    }
}

// ---------------------------------------------------------------------------
// Weight split into FRAGMENT-ORDER global layout.
// Wf element index for (kk, f, l, e) = ((kk*16 + f)*64 + l)*8 + e
//   holds W[kk*32 + (l>>4)*8 + e][f*16 + (l&15)]   (W row-major [K][256])
// ---------------------------------------------------------------------------
__global__ __launch_bounds__(256) void wsplit_frag_kernel(const float* __restrict__ W,
                                                          short* __restrict__ Wh,
                                                          short* __restrict__ Wl,
                                                          int K) {
    int t = blockIdx.x * 256 + threadIdx.x;          // (K/32)*1024 threads
    if (t >= (K >> 5) * 1024) return;
    int l = t & 63;
    int f = (t >> 6) & 15;
    int kk = t >> 10;
    int n = f * 16 + (l & 15);
    int kbase = kk * 32 + ((l >> 4) << 3);
    short8 hi, lo;
#pragma unroll
    for (int e = 0; e < 8; ++e) {
        float v = W[(size_t)(kbase + e) * 256 + n];
        short h = f32_to_bf16_rne(v);
        hi[e] = h;
        lo[e] = f32_to_bf16_rne(v - bf16_to_f32(h));
    }
    *(short8*)&Wh[(size_t)t * 8] = hi;
    *(short8*)&Wl[(size_t)t * 8] = lo;
}

// ---------------------------------------------------------------------------
// MFMA GEMM with fused row-scale:  C[M,256] = (A[M,K] @ W[K,256]) * dinv[row]
// acc += Ah*Bh + Ah*Bl + Al*Bh   (bf16x3 split product)
// Block: 256 threads = 4 waves; tile 64(M) x 256(N); wave tile 64x64.
//
// Round-5 verified two-barrier skeleton; NEW: A(kk+1) global loads issued at
// the top of iter kk into named register slots (n0,n1), consumed by the
// convert of iter kk+1.  B(kk) loads issued first so the compiler's FIFO
// vmcnt wait for B does not drain the A prefetch.  All LDS writes/reads stay
// within one barrier pair (single 8 KB A buffer) -> no new sync semantics.
// ---------------------------------------------------------------------------
__global__ __launch_bounds__(256) void mfma_gemm_kernel(const float* __restrict__ A,
                                                        const short* __restrict__ Bhf,
                                                        const short* __restrict__ Blf,
                                                        const float* __restrict__ dinv,
                                                        float* __restrict__ C,
                                                        int M, int K) {
    __shared__ __align__(16) short AhS[BM * BK];        // 4 KB
    __shared__ __align__(16) short AlS[BM * BK];        // 4 KB

    const int tid  = threadIdx.x;
    const int lane = tid & 63;
    const int wid  = tid >> 6;            // N quadrant
    const int row0 = blockIdx.x * BM;

    // A staging map: 4 lanes per row, thread covers float4 q=(tid&3) and q+4
    const int a_row = tid >> 2;
    const bool arow_ok = (row0 + a_row) < M;
    const float* Aptr = A + (size_t)(row0 + a_row) * K + (tid & 3) * 4;
    // LDS fragment-order slot for q=(tid&3)  (q+4 slot is +256 shorts)
    const int s0 = ((a_row >> 4) * 64 + ((tid & 3) >> 1) * 16 + (a_row & 15)) * 8
                 + ((tid & 3) & 1) * 4;

    // B fragment base for this wave (fragment-order global W)
    const short* BhP = Bhf + ((size_t)(wid * 4) * 64 + lane) * 8;
    const short* BlP = Blf + ((size_t)(wid * 4) * 64 + lane) * 8;

    f32x4 acc[4][4];
#pragma unroll
    for (int i = 0; i < 4; ++i)
#pragma unroll
        for (int j = 0; j < 4; ++j) acc[i][j] = (f32x4){0.f, 0.f, 0.f, 0.f};

    const int nk = K >> 5;

#define LOADA(v0, v1, kkq) do {                                   \
        int kc_ = (kkq) < nk ? (kkq) : nk - 1;                    \
        if (arow_ok) {                                            \
            v0 = *(const float4*)(Aptr + kc_ * 32);               \
            v1 = *(const float4*)(Aptr + kc_ * 32 + 16);          \
        } else {                                                  \
            v0 = make_float4(0.f, 0.f, 0.f, 0.f); v1 = v0;        \
        }                                                         \
    } while (0)

    float4 c0, c1, n0, n1;                // current / next A prefetch slots
    LOADA(c0, c1, 0);

    for (int kk = 0; kk < nk; ++kk) {
        // ---- B(kk) fragments -> regs, issued FIRST (L2-resident) ----
        const short* bhp = BhP + (size_t)kk * BSTEP;
        const short* blp = BlP + (size_t)kk * BSTEP;
        short8 bh[4], bl[4];
#pragma unroll
        for (int nf = 0; nf < 4; ++nf) {
            bh[nf] = *(const short8*)(bhp + nf * 512);
            bl[nf] = *(const short8*)(blp + nf * 512);
        }
        // ---- issue A(kk+1) prefetch (in flight across both barriers) ----
        LOADA(n0, n1, kk + 1);

        // ---- convert A(kk) (loaded one iter ago) + stage to LDS ----
        {
            short4v h0, l0, h1, l1;
            cvt_split4(c0, h0, l0);
            cvt_split4(c1, h1, l1);
            *(short4v*)&AhS[s0]       = h0;
            *(short4v*)&AlS[s0]       = l0;
            *(short4v*)&AhS[s0 + 256] = h1;
            *(short4v*)&AlS[s0 + 256] = l1;
        }
        __syncthreads();

        // ---- A fragments (wave-contiguous 1KB ds_read_b128) + MFMA ----
        short8 ah[4], al[4];
#pragma unroll
        for (int mf = 0; mf < 4; ++mf) {
            ah[mf] = *(const short8*)&AhS[(mf * 64 + lane) * 8];
            al[mf] = *(const short8*)&AlS[(mf * 64 + lane) * 8];
        }
#pragma unroll
        for (int nf = 0; nf < 4; ++nf)
#pragma unroll
            for (int mf = 0; mf < 4; ++mf) {
                acc[mf][nf] = __builtin_amdgcn_mfma_f32_16x16x32_bf16(ah[mf], bh[nf], acc[mf][nf], 0, 0, 0);
                acc[mf][nf] = __builtin_amdgcn_mfma_f32_16x16x32_bf16(ah[mf], bl[nf], acc[mf][nf], 0, 0, 0);
                acc[mf][nf] = __builtin_amdgcn_mfma_f32_16x16x32_bf16(al[mf], bh[nf], acc[mf][nf], 0, 0, 0);
            }
        __syncthreads();   // protect LDS reads from next iter's writes

        c0 = n0; c1 = n1;  // roll prefetch slots (named regs, no indexing)
    }
#undef LOADA

    // ---- C write: col = lane&15, row = (lane>>4)*4 + r ----
    const int lr = lane & 15;
    const int kb = lane >> 4;
#pragma unroll
    for (int mf = 0; mf < 4; ++mf) {
#pragma unroll
        for (int r = 0; r < 4; ++r) {
            int grow = row0 + mf * 16 + kb * 4 + r;
            if (grow < M) {
                float dd = dinv[grow];
                float* cp = &C[(size_t)grow * C_OUT + wid * 64 + lr];
#pragma unroll
                for (int nf = 0; nf < 4; ++nf) cp[nf * 16] = acc[mf][nf][r] * dd;
            }
        }
    }
}

// ---------------------------------------------------------------------------
// CSR aggregation, one wave per node, 4-deep unroll (4 independent gathers
// in flight).   out[d] = dinv[d]*(hs[d] + sum_{s in N(d)} hs[s]) + b  [+relu]
// ---------------------------------------------------------------------------
__global__ __launch_bounds__(256) void agg_kernel(const float* __restrict__ hs,
                                                  const int* __restrict__ rowstart,
                                                  const int* __restrict__ srcSorted,
                                                  const float* __restrict__ dinv,
                                                  const float* __restrict__ bias,
                                                  float* __restrict__ out,
                                                  int n, int do_relu) {
    int node = blockIdx.x * 4 + (threadIdx.x >> 6);
    if (node >= n) return;
    int q = threadIdx.x & 63;                      // float4 index within row
    const f32x4* base = (const f32x4*)hs;

    f32x4 acc0 = base[(size_t)node * 64 + q];      // self-loop term
    f32x4 acc1 = (f32x4){0.f, 0.f, 0.f, 0.f};
    f32x4 acc2 = (f32x4){0.f, 0.f, 0.f, 0.f};
    f32x4 acc3 = (f32x4){0.f, 0.f, 0.f, 0.f};
    int i0 = rowstart[node];
    int i1 = rowstart[node + 1];
    int i = i0;
    for (; i + 3 < i1; i += 4) {
        int s0 = srcSorted[i];
        int s1 = srcSorted[i + 1];
        int s2 = srcSorted[i + 2];
        int s3 = srcSorted[i + 3];
        acc0 += base[(size_t)s0 * 64 + q];
        acc1 += base[(size_t)s1 * 64 + q];
        acc2 += base[(size_t)s2 * 64 + q];
        acc3 += base[(size_t)s3 * 64 + q];
    }
    for (; i < i1; ++i) acc0 += base[(size_t)srcSorted[i] * 64 + q];

    float dd = dinv[node];
    f32x4 bv = *(const f32x4*)&bias[q << 2];
    f32x4 r = ((acc0 + acc1) + (acc2 + acc3)) * dd + bv;
    if (do_relu) {
        r[0] = fmaxf(r[0], 0.f); r[1] = fmaxf(r[1], 0.f);
        r[2] = fmaxf(r[2], 0.f); r[3] = fmaxf(r[3], 0.f);
    }
    ((f32x4*)out)[(size_t)node * 64 + q] = r;
}

extern "C" void kernel_launch(void* const* d_in, const int* in_sizes, int n_in,
                              void* d_out, int out_size, void* d_ws, size_t ws_size,
                              hipStream_t stream) {
    const float* x  = (const float*)d_in[0];
    const int* ei   = (const int*)d_in[1];
    const float* W1 = (const float*)d_in[2];
    const float* b1 = (const float*)d_in[3];
    const float* W2 = (const float*)d_in[4];
    const float* b2 = (const float*)d_in[5];
    float* out = (float*)d_out;

    const int K1 = 768;
    const int N  = in_sizes[0] / K1;        // 50000
    const int nE = in_sizes[1] / 2;         // 800000
    const int* src = ei;
    const int* dst = ei + nE;

    // workspace layout (256B-aligned chunks)
    char* ws = (char*)d_ws;
    size_t off = 0;
    auto alloc = [&](size_t bytes) { void* p = ws + off; off += (bytes + 255) & ~255ull; return p; };
    float* dinv      = (float*)alloc((size_t)N * 4);
    float* bufA      = (float*)alloc((size_t)N * C_OUT * 4);   // hs1 / hs2
    float* bufB      = (float*)alloc((size_t)N * C_OUT * 4);   // h1
    short* Wh1       = (short*)alloc((size_t)768 * 256 * 2);   // fragment order
    short* Wl1       = (short*)alloc((size_t)768 * 256 * 2);
    short* Wh2       = (short*)alloc((size_t)256 * 256 * 2);
    short* Wl2       = (short*)alloc((size_t)256 * 256 * 2);
    int*   count     = (int*)alloc((size_t)N * 4);
    int*   rowpart   = (int*)alloc((size_t)N * 4);
    int*   rowstart  = (int*)alloc((size_t)(N + 1) * 4);
    int*   cursor    = (int*)alloc((size_t)N * 4);
    int*   bsums     = (int*)alloc(256 * 4);
    int*   srcSorted = (int*)alloc((size_t)nE * 4);

    const int nbN = (N + 255) / 256;        // 196 blocks (fits scan2's 256 cap)
    const int nbE = (nE + 255) / 256;
    const int gemm_blocks = (N + BM - 1) / BM;
    const int agg_blocks = (N + 3) / 4;

    // ---- CSR build + dinv ----
    hipMemsetAsync(count, 0, (size_t)N * 4, stream);
    count_kernel<<<nbE, 256, 0, stream>>>(dst, count, nE);
    scan1_kernel<<<nbN, 256, 0, stream>>>(count, rowpart, bsums, N);
    scan2_kernel<<<1, 256, 0, stream>>>(bsums, nbN);
    scan3_kernel<<<nbN, 256, 0, stream>>>(rowpart, bsums, count, rowstart, cursor, dinv, N, nE);
    fill_kernel<<<nbE, 256, 0, stream>>>(src, dst, cursor, srcSorted, nE);

    // ---- weight split into fragment order ----
    wsplit_frag_kernel<<<(768 / 32 * 1024 + 255) / 256, 256, 0, stream>>>(W1, Wh1, Wl1, 768);
    wsplit_frag_kernel<<<(256 / 32 * 1024 + 255) / 256, 256, 0, stream>>>(W2, Wh2, Wl2, 256);

    // ---- layer 1 ----
    mfma_gemm_kernel<<<gemm_blocks, 256, 0, stream>>>(x, Wh1, Wl1, dinv, bufA, N, K1);
    agg_kernel<<<agg_blocks, 256, 0, stream>>>(bufA, rowstart, srcSorted, dinv, b1, bufB, N, 1);

    // ---- layer 2 ----
    mfma_gemm_kernel<<<gemm_blocks, 256, 0, stream>>>(bufB, Wh2, Wl2, dinv, bufA, N, C_OUT);
    agg_kernel<<<agg_blocks, 256, 0, stream>>>(bufA, rowstart, srcSorted, dinv, b2, out, N, 0);
}

// Round 9
// 525.410 us; speedup vs baseline: 11.0253x; 1.2354x over previous
//
#include <hip/hip_runtime.h>
#include <hip/hip_bf16.h>
#include <stdint.h>

// ---------------------------------------------------------------------------
// 2-layer GCN on MI355X (gfx950).  Round 9: bf16 edge messages.  The CSR
// aggregation is BW-bound on the L2-miss path (R8: 460 MB @ 3.75 TB/s) ->
// halve its bytes by storing the GEMM outputs (agg inputs) as bf16.
// fp32 accumulation; h1 (GEMM2 input) stays fp32 -> GEMM path unchanged.
//
//   count[d] = in-degree ; dinv = rsqrt(count+1)
//   CSR: rowstart = exscan(count) ; srcSorted bucketed by dst
//   hs1 = bf16((x @ W1) * dinv[row])                 (MFMA GEMM, fused scale)
//   h1  = relu(dinv[d]*(hs1[d] + sum_{s->d} hs1[s]) + b1)   fp32
//   hs2 = bf16((h1 @ W2) * dinv[row])
//   out = dinv[d]*(hs2[d] + sum hs2[s]) + b2                fp32
// ---------------------------------------------------------------------------

#define C_OUT 256
#define BM 64          // GEMM rows per block
#define BK 32          // GEMM k-step
#define BSTEP (16 * 64 * 8)   // shorts per K-step in fragment-order W

typedef short  short8  __attribute__((ext_vector_type(8)));
typedef short  short4v __attribute__((ext_vector_type(4)));
typedef float  f32x4   __attribute__((ext_vector_type(4)));

static __device__ __forceinline__ short f32_to_bf16_rne(float f) {
    uint32_t u = __builtin_bit_cast(uint32_t, f);
    uint32_t r = 0x7FFFu + ((u >> 16) & 1u);
    return (short)((u + r) >> 16);
}
static __device__ __forceinline__ float bf16_to_f32(short s) {
    uint32_t u = ((uint32_t)(uint16_t)s) << 16;
    return __builtin_bit_cast(float, u);
}
static __device__ __forceinline__ void cvt_split4(float4 v, short4v& hi, short4v& lo) {
    float f[4] = {v.x, v.y, v.z, v.w};
#pragma unroll
    for (int j = 0; j < 4; ++j) {
        short h = f32_to_bf16_rne(f[j]);
        hi[j] = h;
        lo[j] = f32_to_bf16_rne(f[j] - bf16_to_f32(h));
    }
}
static __device__ __forceinline__ f32x4 bf16x4_to_f32x4(short4v v) {
    return (f32x4){bf16_to_f32(v[0]), bf16_to_f32(v[1]),
                   bf16_to_f32(v[2]), bf16_to_f32(v[3])};
}

// --------------------------- CSR build ------------------------------------
__global__ __launch_bounds__(256) void count_kernel(const int* __restrict__ dst,
                                                    int* __restrict__ count, int nE) {
    int e = blockIdx.x * blockDim.x + threadIdx.x;
    if (e < nE) atomicAdd(&count[dst[e]], 1);
}

__global__ __launch_bounds__(256) void scan1_kernel(const int* __restrict__ count,
                                                    int* __restrict__ rowpart,
                                                    int* __restrict__ bsums, int n) {
    __shared__ int tmp[256];
    int t = threadIdx.x;
    int i = blockIdx.x * 256 + t;
    int v = (i < n) ? count[i] : 0;
    tmp[t] = v;
    __syncthreads();
    for (int off = 1; off < 256; off <<= 1) {
        int u = 0;
        if (t >= off) u = tmp[t - off];
        __syncthreads();
        if (t >= off) tmp[t] += u;
        __syncthreads();
    }
    if (i < n) rowpart[i] = tmp[t] - v;          // exclusive
    if (t == 255) bsums[blockIdx.x] = tmp[255];  // block total
}

__global__ __launch_bounds__(256) void scan2_kernel(int* __restrict__ bsums, int nb) {
    __shared__ int tmp[256];
    int t = threadIdx.x;
    int v = (t < nb) ? bsums[t] : 0;
    tmp[t] = v;
    __syncthreads();
    for (int off = 1; off < 256; off <<= 1) {
        int u = 0;
        if (t >= off) u = tmp[t - off];
        __syncthreads();
        if (t >= off) tmp[t] += u;
        __syncthreads();
    }
    if (t < nb) bsums[t] = tmp[t] - v;           // exclusive, in-place
}

__global__ __launch_bounds__(256) void scan3_kernel(const int* __restrict__ rowpart,
                                                    const int* __restrict__ bsums,
                                                    const int* __restrict__ count,
                                                    int* __restrict__ rowstart,
                                                    int* __restrict__ cursor,
                                                    float* __restrict__ dinv,
                                                    int n, int nE) {
    int i = blockIdx.x * 256 + threadIdx.x;
    if (i < n) {
        int r = rowpart[i] + bsums[blockIdx.x];
        rowstart[i] = r;
        cursor[i] = r;
        dinv[i] = rsqrtf((float)count[i] + 1.0f);
    }
    if (i == 0) rowstart[n] = nE;
}

__global__ __launch_bounds__(256) void fill_kernel(const int* __restrict__ src,
                                                   const int* __restrict__ dst,
                                                   int* __restrict__ cursor,
                                                   int* __restrict__ srcSorted, int nE) {
    int e = blockIdx.x * blockDim.x + threadIdx.x;
    if (e < nE) {
        int p = atomicAdd(&cursor[dst[e]], 1);
        srcSorted[p] = src[e];
    }
}

// ---------------------------------------------------------------------------
// Weight split into FRAGMENT-ORDER global layout.
// Wf element index for (kk, f, l, e) = ((kk*16 + f)*64 + l)*8 + e
//   holds W[kk*32 + (l>>4)*8 + e][f*16 + (l&15)]   (W row-major [K][256])
// ---------------------------------------------------------------------------
__global__ __launch_bounds__(256) void wsplit_frag_kernel(const float* __restrict__ W,
                                                          short* __restrict__ Wh,
                                                          short* __restrict__ Wl,
                                                          int K) {
    int t = blockIdx.x * 256 + threadIdx.x;          // (K/32)*1024 threads
    if (t >= (K >> 5) * 1024) return;
    int l = t & 63;
    int f = (t >> 6) & 15;
    int kk = t >> 10;
    int n = f * 16 + (l & 15);
    int kbase = kk * 32 + ((l >> 4) << 3);
    short8 hi, lo;
#pragma unroll
    for (int e = 0; e < 8; ++e) {
        float v = W[(size_t)(kbase + e) * 256 + n];
        short h = f32_to_bf16_rne(v);
        hi[e] = h;
        lo[e] = f32_to_bf16_rne(v - bf16_to_f32(h));
    }
    *(short8*)&Wh[(size_t)t * 8] = hi;
    *(short8*)&Wl[(size_t)t * 8] = lo;
}

// ---------------------------------------------------------------------------
// MFMA GEMM with fused row-scale, bf16 OUTPUT:
//   C[M,256] = bf16( (A[M,K] @ W[K,256]) * dinv[row] )
// acc += Ah*Bh + Ah*Bl + Al*Bh   (bf16x3 split product, fp32 accum)
// Block: 256 threads = 4 waves; tile 64(M) x 256(N); wave tile 64x64.
// Two-barrier verified skeleton + reg-only A(kk+1) prefetch (R8).
// ---------------------------------------------------------------------------
__global__ __launch_bounds__(256) void mfma_gemm_kernel(const float* __restrict__ A,
                                                        const short* __restrict__ Bhf,
                                                        const short* __restrict__ Blf,
                                                        const float* __restrict__ dinv,
                                                        unsigned short* __restrict__ C,
                                                        int M, int K) {
    __shared__ __align__(16) short AhS[BM * BK];        // 4 KB
    __shared__ __align__(16) short AlS[BM * BK];        // 4 KB

    const int tid  = threadIdx.x;
    const int lane = tid & 63;
    const int wid  = tid >> 6;            // N quadrant
    const int row0 = blockIdx.x * BM;

    // A staging map: 4 lanes per row, thread covers float4 q=(tid&3) and q+4
    const int a_row = tid >> 2;
    const bool arow_ok = (row0 + a_row) < M;
    const float* Aptr = A + (size_t)(row0 + a_row) * K + (tid & 3) * 4;
    // LDS fragment-order slot for q=(tid&3)  (q+4 slot is +256 shorts)
    const int s0 = ((a_row >> 4) * 64 + ((tid & 3) >> 1) * 16 + (a_row & 15)) * 8
                 + ((tid & 3) & 1) * 4;

    // B fragment base for this wave (fragment-order global W)
    const short* BhP = Bhf + ((size_t)(wid * 4) * 64 + lane) * 8;
    const short* BlP = Blf + ((size_t)(wid * 4) * 64 + lane) * 8;

    f32x4 acc[4][4];
#pragma unroll
    for (int i = 0; i < 4; ++i)
#pragma unroll
        for (int j = 0; j < 4; ++j) acc[i][j] = (f32x4){0.f, 0.f, 0.f, 0.f};

    const int nk = K >> 5;

#define LOADA(v0, v1, kkq) do {                                   \
        int kc_ = (kkq) < nk ? (kkq) : nk - 1;                    \
        if (arow_ok) {                                            \
            v0 = *(const float4*)(Aptr + kc_ * 32);               \
            v1 = *(const float4*)(Aptr + kc_ * 32 + 16);          \
        } else {                                                  \
            v0 = make_float4(0.f, 0.f, 0.f, 0.f); v1 = v0;        \
        }                                                         \
    } while (0)

    float4 c0, c1, n0, n1;                // current / next A prefetch slots
    LOADA(c0, c1, 0);

    for (int kk = 0; kk < nk; ++kk) {
        // ---- B(kk) fragments -> regs, issued FIRST (L2-resident) ----
        const short* bhp = BhP + (size_t)kk * BSTEP;
        const short* blp = BlP + (size_t)kk * BSTEP;
        short8 bh[4], bl[4];
#pragma unroll
        for (int nf = 0; nf < 4; ++nf) {
            bh[nf] = *(const short8*)(bhp + nf * 512);
            bl[nf] = *(const short8*)(blp + nf * 512);
        }
        // ---- issue A(kk+1) prefetch (in flight across both barriers) ----
        LOADA(n0, n1, kk + 1);

        // ---- convert A(kk) (loaded one iter ago) + stage to LDS ----
        {
            short4v h0, l0, h1, l1;
            cvt_split4(c0, h0, l0);
            cvt_split4(c1, h1, l1);
            *(short4v*)&AhS[s0]       = h0;
            *(short4v*)&AlS[s0]       = l0;
            *(short4v*)&AhS[s0 + 256] = h1;
            *(short4v*)&AlS[s0 + 256] = l1;
        }
        __syncthreads();

        // ---- A fragments (wave-contiguous 1KB ds_read_b128) + MFMA ----
        short8 ah[4], al[4];
#pragma unroll
        for (int mf = 0; mf < 4; ++mf) {
            ah[mf] = *(const short8*)&AhS[(mf * 64 + lane) * 8];
            al[mf] = *(const short8*)&AlS[(mf * 64 + lane) * 8];
        }
#pragma unroll
        for (int nf = 0; nf < 4; ++nf)
#pragma unroll
            for (int mf = 0; mf < 4; ++mf) {
                acc[mf][nf] = __builtin_amdgcn_mfma_f32_16x16x32_bf16(ah[mf], bh[nf], acc[mf][nf], 0, 0, 0);
                acc[mf][nf] = __builtin_amdgcn_mfma_f32_16x16x32_bf16(ah[mf], bl[nf], acc[mf][nf], 0, 0, 0);
                acc[mf][nf] = __builtin_amdgcn_mfma_f32_16x16x32_bf16(al[mf], bh[nf], acc[mf][nf], 0, 0, 0);
            }
        __syncthreads();   // protect LDS reads from next iter's writes

        c0 = n0; c1 = n1;  // roll prefetch slots (named regs, no indexing)
    }
#undef LOADA

    // ---- C write (bf16): col = lane&15, row = (lane>>4)*4 + r ----
    const int lr = lane & 15;
    const int kb = lane >> 4;
#pragma unroll
    for (int mf = 0; mf < 4; ++mf) {
#pragma unroll
        for (int r = 0; r < 4; ++r) {
            int grow = row0 + mf * 16 + kb * 4 + r;
            if (grow < M) {
                float dd = dinv[grow];
                unsigned short* cp = &C[(size_t)grow * C_OUT + wid * 64 + lr];
#pragma unroll
                for (int nf = 0; nf < 4; ++nf)
                    cp[nf * 16] = (unsigned short)f32_to_bf16_rne(acc[mf][nf][r] * dd);
            }
        }
    }
}

// ---------------------------------------------------------------------------
// CSR aggregation over bf16 messages, one wave per node, 4-deep unroll.
//   out[d] = dinv[d]*(hs[d] + sum_{s in N(d)} hs[s]) + b  [+relu]   fp32 accum
// Lane q covers channels 4q..4q+3: gathers 8B (ushort4), 64 lanes = 512B/row.
// ---------------------------------------------------------------------------
__global__ __launch_bounds__(256) void agg_kernel(const unsigned short* __restrict__ hs,
                                                  const int* __restrict__ rowstart,
                                                  const int* __restrict__ srcSorted,
                                                  const float* __restrict__ dinv,
                                                  const float* __restrict__ bias,
                                                  float* __restrict__ out,
                                                  int n, int do_relu) {
    int node = blockIdx.x * 4 + (threadIdx.x >> 6);
    if (node >= n) return;
    int q = threadIdx.x & 63;                      // 4-channel group index
    const int qo = q << 2;

    f32x4 acc0 = bf16x4_to_f32x4(*(const short4v*)&hs[((size_t)node << 8) + qo]);
    f32x4 acc1 = (f32x4){0.f, 0.f, 0.f, 0.f};
    f32x4 acc2 = (f32x4){0.f, 0.f, 0.f, 0.f};
    f32x4 acc3 = (f32x4){0.f, 0.f, 0.f, 0.f};
    int i0 = rowstart[node];
    int i1 = rowstart[node + 1];
    int i = i0;
    for (; i + 3 < i1; i += 4) {
        int s0 = srcSorted[i];
        int s1 = srcSorted[i + 1];
        int s2 = srcSorted[i + 2];
        int s3 = srcSorted[i + 3];
        short4v v0 = *(const short4v*)&hs[((size_t)s0 << 8) + qo];
        short4v v1 = *(const short4v*)&hs[((size_t)s1 << 8) + qo];
        short4v v2 = *(const short4v*)&hs[((size_t)s2 << 8) + qo];
        short4v v3 = *(const short4v*)&hs[((size_t)s3 << 8) + qo];
        acc0 += bf16x4_to_f32x4(v0);
        acc1 += bf16x4_to_f32x4(v1);
        acc2 += bf16x4_to_f32x4(v2);
        acc3 += bf16x4_to_f32x4(v3);
    }
    for (; i < i1; ++i)
        acc0 += bf16x4_to_f32x4(*(const short4v*)&hs[((size_t)srcSorted[i] << 8) + qo]);

    float dd = dinv[node];
    f32x4 bv = *(const f32x4*)&bias[qo];
    f32x4 r = ((acc0 + acc1) + (acc2 + acc3)) * dd + bv;
    if (do_relu) {
        r[0] = fmaxf(r[0], 0.f); r[1] = fmaxf(r[1], 0.f);
        r[2] = fmaxf(r[2], 0.f); r[3] = fmaxf(r[3], 0.f);
    }
    ((f32x4*)out)[(size_t)node * 64 + q] = r;
}

extern "C" void kernel_launch(void* const* d_in, const int* in_sizes, int n_in,
                              void* d_out, int out_size, void* d_ws, size_t ws_size,
                              hipStream_t stream) {
    const float* x  = (const float*)d_in[0];
    const int* ei   = (const int*)d_in[1];
    const float* W1 = (const float*)d_in[2];
    const float* b1 = (const float*)d_in[3];
    const float* W2 = (const float*)d_in[4];
    const float* b2 = (const float*)d_in[5];
    float* out = (float*)d_out;

    const int K1 = 768;
    const int N  = in_sizes[0] / K1;        // 50000
    const int nE = in_sizes[1] / 2;         // 800000
    const int* src = ei;
    const int* dst = ei + nE;

    // workspace layout (256B-aligned chunks)
    char* ws = (char*)d_ws;
    size_t off = 0;
    auto alloc = [&](size_t bytes) { void* p = ws + off; off += (bytes + 255) & ~255ull; return p; };
    float*          dinv      = (float*)alloc((size_t)N * 4);
    unsigned short* hsbuf     = (unsigned short*)alloc((size_t)N * C_OUT * 2); // hs1/hs2 bf16
    float*          h1buf     = (float*)alloc((size_t)N * C_OUT * 4);          // h1 fp32
    short* Wh1       = (short*)alloc((size_t)768 * 256 * 2);   // fragment order
    short* Wl1       = (short*)alloc((size_t)768 * 256 * 2);
    short* Wh2       = (short*)alloc((size_t)256 * 256 * 2);
    short* Wl2       = (short*)alloc((size_t)256 * 256 * 2);
    int*   count     = (int*)alloc((size_t)N * 4);
    int*   rowpart   = (int*)alloc((size_t)N * 4);
    int*   rowstart  = (int*)alloc((size_t)(N + 1) * 4);
    int*   cursor    = (int*)alloc((size_t)N * 4);
    int*   bsums     = (int*)alloc(256 * 4);
    int*   srcSorted = (int*)alloc((size_t)nE * 4);

    const int nbN = (N + 255) / 256;        // 196 blocks (fits scan2's 256 cap)
    const int nbE = (nE + 255) / 256;
    const int gemm_blocks = (N + BM - 1) / BM;
    const int agg_blocks = (N + 3) / 4;

    // ---- CSR build + dinv ----
    hipMemsetAsync(count, 0, (size_t)N * 4, stream);
    count_kernel<<<nbE, 256, 0, stream>>>(dst, count, nE);
    scan1_kernel<<<nbN, 256, 0, stream>>>(count, rowpart, bsums, N);
    scan2_kernel<<<1, 256, 0, stream>>>(bsums, nbN);
    scan3_kernel<<<nbN, 256, 0, stream>>>(rowpart, bsums, count, rowstart, cursor, dinv, N, nE);
    fill_kernel<<<nbE, 256, 0, stream>>>(src, dst, cursor, srcSorted, nE);

    // ---- weight split into fragment order ----
    wsplit_frag_kernel<<<(768 / 32 * 1024 + 255) / 256, 256, 0, stream>>>(W1, Wh1, Wl1, 768);
    wsplit_frag_kernel<<<(256 / 32 * 1024 + 255) / 256, 256, 0, stream>>>(W2, Wh2, Wl2, 256);

    // ---- layer 1 ----
    mfma_gemm_kernel<<<gemm_blocks, 256, 0, stream>>>(x, Wh1, Wl1, dinv, hsbuf, N, K1);
    agg_kernel<<<agg_blocks, 256, 0, stream>>>(hsbuf, rowstart, srcSorted, dinv, b1, h1buf, N, 1);

    // ---- layer 2 ----
    mfma_gemm_kernel<<<gemm_blocks, 256, 0, stream>>>(h1buf, Wh2, Wl2, dinv, hsbuf, N, C_OUT);
    agg_kernel<<<agg_blocks, 256, 0, stream>>>(hsbuf, rowstart, srcSorted, dinv, b2, out, N, 0);
}